// Round 3
// baseline (885.731 us; speedup 1.0000x reference)
//
#include <hip/hip_runtime.h>
#include <hip/hip_fp16.h>
#include <stdint.h>

#define B_TOT 131072
#define CHUNK 65536
#define NH 16
#define NC 32
#define HIDD 512

typedef unsigned short u16;
typedef __attribute__((ext_vector_type(8))) short short8;
typedef __attribute__((ext_vector_type(4))) float f32x4;
typedef __attribute__((ext_vector_type(4))) int i32x4;

__device__ __forceinline__ u16 f2bf(float x){
  unsigned u = __float_as_uint(x);
  u += 0x7fffu + ((u >> 16) & 1u);
  return (u16)(u >> 16);
}
__device__ __forceinline__ float bf2f(u16 b){ return __uint_as_float(((unsigned)b) << 16); }
__device__ __forceinline__ u16 f2h(float x){ __half h = __float2half(x); return *(u16*)&h; }
__device__ __forceinline__ float h2f(u16 b){ __half h; *(u16*)&h = b; return __half2float(h); }
// mish(x) = x*tanh(softplus(x)); tanh(log(1+e^x)) == (u^2-1)/(u^2+1), u = 1+e^x (exact identity)
__device__ __forceinline__ float mishf(float x){
  float e = __expf(fminf(x, 30.f));
  float u = 1.f + e;
  float u2 = u * u;
  return x * (u2 - 1.f) / (u2 + 1.f);
}
__device__ __forceinline__ float bfly_max16(float x){
#pragma unroll
  for (int s = 1; s < 16; s <<= 1) x = fmaxf(x, __shfl_xor(x, s));
  return x;
}
__device__ __forceinline__ float bfly_sum16(float x){
#pragma unroll
  for (int s = 1; s < 16; s <<= 1) x += __shfl_xor(x, s);
  return x;
}

// ---------------- prep kernels ----------------
__global__ void prep_small(const float* __restrict__ deltas, const float* __restrict__ Wa,
                           const float* __restrict__ Wo, float* __restrict__ cps, float* __restrict__ wWo)
{
  const int t = threadIdx.x;
  if (t < NH){
    float cum[NC];
    float run = 0.f;
#pragma unroll
    for (int c = 0; c < NC; c++){
      float d = deltas[t*NC + c];
      float sp = (d > 20.f) ? d : log1pf(__expf(d));
      run += sp; cum[c] = run;
    }
    float s = 365.0f / run;
#pragma unroll
    for (int c = 0; c < NC; c++) cps[t*NC + c] = cum[c] * s;
  } else if (t >= 64 && t < 128){
    const int k = t - 64;
    float s = 0.f;
    for (int n = 0; n < HIDD; n++) s += Wa[k*HIDD + n] * Wo[n];
    wWo[k] = s;
  }
}

__global__ void prep_convert(const float* __restrict__ Wah, const float* __restrict__ Waa,
                             const float* __restrict__ Wb, const float* __restrict__ Wh,
                             u16* __restrict__ WahT, u16* __restrict__ WaaT,
                             u16* __restrict__ WbT, u16* __restrict__ WhT)
{
  int i = blockIdx.x * 256 + threadIdx.x;
  if (i < 262144){ int n = i >> 9, k = i & 511; WahT[i] = f2bf(Wah[k*512 + n]); return; }
  i -= 262144;
  if (i < 262144){ int n = i >> 9, k = i & 511; WaaT[i] = f2bf(Waa[k*512 + n]); return; }
  i -= 262144;
  if (i < 32768){ int n = i >> 6, k = i & 63; WbT[i] = f2bf(Wb[k*512 + n]); return; }
  i -= 32768;
  if (i < 16384){ int h = i >> 10, r = i & 1023, d = r >> 5, c = r & 31;
                  WhT[i] = f2bf(Wh[h*1024 + c*32 + d]); return; }
}

// ---------------- stage 1: feats -> LN -> softmax -> einsum(MFMA) -> mish ----------------
__global__ __launch_bounds__(256) void stage1_kernel(
    const float* __restrict__ inputs, const float* __restrict__ sku,
    const float* __restrict__ ln_g, const float* __restrict__ ln_b,
    const float* __restrict__ attnw, const float* __restrict__ cps,
    const u16* __restrict__ WhT, u16* __restrict__ agg, u16* __restrict__ skub)
{
  __shared__ __align__(16) float in_l[256];
  __shared__ __align__(16) float cps_l[512];
  __shared__ __align__(16) float gam_l[512];
  __shared__ __align__(16) float bet_l[512];
  __shared__ float aw_l[16];
  __shared__ __align__(16) u16 at_l[16*16*32];   // [h][b16][c32]
  __shared__ __align__(16) u16 ot_l[16*512];     // [b16][512]

  const int t = threadIdx.x;
  const long bb = (long)blockIdx.x * 16;

  in_l[t] = inputs[bb*16 + t];
  cps_l[t] = cps[t];       cps_l[t+256] = cps[t+256];
  gam_l[t] = ln_g[t];      gam_l[t+256] = ln_g[t+256];
  bet_l[t] = ln_b[t];      bet_l[t+256] = ln_b[t+256];
  if (t < 16) aw_l[t] = attnw[t];
  { // sku -> bf16 (16 rows x 64)
    const f32x4 sv = *(const f32x4*)&sku[bb*64 + t*4];
    unsigned lo = (unsigned)f2bf(sv.x) | ((unsigned)f2bf(sv.y) << 16);
    unsigned hi = (unsigned)f2bf(sv.z) | ((unsigned)f2bf(sv.w) << 16);
    unsigned long long v = (unsigned long long)lo | ((unsigned long long)hi << 32);
    *(unsigned long long*)&skub[bb*64 + t*4] = v;
  }
  __syncthreads();

  const int h = t >> 4, bi = t & 15;
  const float x = in_l[bi*16 + h];
  float nrm[NC], pw[NC];
  float s1 = 0.f;
#pragma unroll
  for (int c = 0; c < NC; c++){ float f = fmaxf(x - cps_l[h*NC + c], 0.f); nrm[c] = f; s1 += f; }
  const float mu = s1 * (1.f/NC);
  float s2 = 0.f;
#pragma unroll
  for (int c = 0; c < NC; c++){ float d = nrm[c] - mu; s2 += d*d; }
  const float rs = rsqrtf(s2 * (1.f/NC) + 1e-3f);
  const float aw = aw_l[h] * (1.0f/0.7f);
  float lmax = -1e30f;
#pragma unroll
  for (int c = 0; c < NC; c++){
    float nv = (nrm[c] - mu) * rs * gam_l[h*NC + c] + bet_l[h*NC + c];
    nrm[c] = nv;
    lmax = fmaxf(lmax, nv * aw);
  }
  float ps = 0.f;
#pragma unroll
  for (int c = 0; c < NC; c++){ float p = __expf(nrm[c]*aw - lmax); pw[c] = p; ps += p; }
  const float invs = 1.f / ps;
#pragma unroll
  for (int c = 0; c < NC; c += 2){
    unsigned pk = (unsigned)f2bf(nrm[c]*pw[c]*invs) | ((unsigned)f2bf(nrm[c+1]*pw[c+1]*invs) << 16);
    *(unsigned*)&at_l[h*512 + bi*32 + c] = pk;
  }
  __syncthreads();

  const int wv = t >> 6, ln = t & 63;
  const int lrow = ln & 15, lq = ln >> 4;
#pragma unroll
  for (int q = 0; q < 4; q++){
    const int hh = wv*4 + q;
    short8 af  = *(const short8*)&at_l[hh*512 + lrow*32 + lq*8];
    short8 bf0 = *(const short8*)&WhT[hh*1024 + lrow*32 + lq*8];
    short8 bf1 = *(const short8*)&WhT[hh*1024 + (16 + lrow)*32 + lq*8];
    f32x4 acc0 = {0.f,0.f,0.f,0.f}, acc1 = {0.f,0.f,0.f,0.f};
    acc0 = __builtin_amdgcn_mfma_f32_16x16x32_bf16(af, bf0, acc0, 0, 0, 0);
    acc1 = __builtin_amdgcn_mfma_f32_16x16x32_bf16(af, bf1, acc1, 0, 0, 0);
#pragma unroll
    for (int r = 0; r < 4; r++){
      const int br = lq*4 + r;
      ot_l[br*512 + hh*32 + lrow]      = f2bf(mishf(acc0[r]));
      ot_l[br*512 + hh*32 + 16 + lrow] = f2bf(mishf(acc1[r]));
    }
  }
  __syncthreads();
  {
    const int row = t >> 4, c16 = t & 15;
    const i32x4* src = (const i32x4*)&ot_l[row*512 + c16*32];
    i32x4* dst = (i32x4*)&agg[(bb + row)*512 + c16*32];
#pragma unroll
    for (int j = 0; j < 4; j++) dst[j] = src[j];
  }
}

// ---------------- LDS-free GEMM, K=512, epilogue mish -> bf16 ----------------
// agg[M][512] @ WahT[512 n][512 k] -> aggh. Barrier-free; frags direct from global (L2-hot B).
__global__ __launch_bounds__(256) void gemm_mish(
    const u16* __restrict__ A, const u16* __restrict__ Bt, u16* __restrict__ outp)
{
  const int t = threadIdx.x, wv = t >> 6, ln = t & 63;
  const int g = blockIdx.x;
  // XCD swizzle: blocks g, g+8, g+16, g+24 (same XCD under round-robin) share one A-stripe
  const int m_idx = (g & 7) + ((g >> 5) << 3);
  const int n_idx = (g >> 3) & 3;
  const long m0 = (long)m_idx * 128;
  const int n0 = n_idx * 128;
  const int lrow = ln & 15, lq = ln >> 4;
  const int wm = wv >> 1, wn = wv & 1;
  const u16* Ap = A  + (m0 + wm*64 + lrow)*512 + lq*8;
  const u16* Bp = Bt + (long)(n0 + wn*64 + lrow)*512 + lq*8;

  short8 a[4], b[4];
#pragma unroll
  for (int i = 0; i < 4; i++){
    a[i] = *(const short8*)(Ap + i*8192);
    b[i] = *(const short8*)(Bp + i*8192);
  }
  f32x4 acc[4][4] = {};
#pragma unroll 1
  for (int ks = 1; ks < 16; ks++){
    short8 na[4], nb[4];
#pragma unroll
    for (int i = 0; i < 4; i++){
      na[i] = *(const short8*)(Ap + i*8192 + ks*32);
      nb[i] = *(const short8*)(Bp + i*8192 + ks*32);
    }
#pragma unroll
    for (int i = 0; i < 4; i++)
#pragma unroll
      for (int j = 0; j < 4; j++)
        acc[i][j] = __builtin_amdgcn_mfma_f32_16x16x32_bf16(a[i], b[j], acc[i][j], 0, 0, 0);
#pragma unroll
    for (int i = 0; i < 4; i++){ a[i] = na[i]; b[i] = nb[i]; }
  }
#pragma unroll
  for (int i = 0; i < 4; i++)
#pragma unroll
    for (int j = 0; j < 4; j++)
      acc[i][j] = __builtin_amdgcn_mfma_f32_16x16x32_bf16(a[i], b[j], acc[i][j], 0, 0, 0);

#pragma unroll
  for (int i = 0; i < 4; i++)
#pragma unroll
    for (int j = 0; j < 4; j++)
#pragma unroll
      for (int r = 0; r < 4; r++){
        const long m = m0 + wm*64 + i*16 + lq*4 + r;
        const int n = n0 + wn*64 + j*16 + lrow;
        outp[m*512 + n] = f2bf(mishf(acc[i][j][r]));
      }
}

// ---------------- LDS-free GEMM, K=64: wprod = sigmoid(sku@Wb) * aggh * Wo (fp16) ----------------
__global__ __launch_bounds__(256) void gemm_beta(
    const u16* __restrict__ A, const u16* __restrict__ Bt, const u16* __restrict__ aggh,
    const float* __restrict__ Wo, u16* __restrict__ wprod)
{
  const int t = threadIdx.x, wv = t >> 6, ln = t & 63;
  const int g = blockIdx.x;
  const int m_idx = (g & 7) + ((g >> 5) << 3);
  const int n_idx = (g >> 3) & 3;
  const long m0 = (long)m_idx * 128;
  const int n0 = n_idx * 128;
  const int lrow = ln & 15, lq = ln >> 4;
  const int wm = wv >> 1, wn = wv & 1;
  const u16* Ap = A  + (m0 + wm*64 + lrow)*64 + lq*8;
  const u16* Bp = Bt + (n0 + wn*64 + lrow)*64 + lq*8;

  f32x4 acc[4][4] = {};
#pragma unroll
  for (int ks = 0; ks < 2; ks++){
    short8 a[4], b[4];
#pragma unroll
    for (int i = 0; i < 4; i++){
      a[i] = *(const short8*)(Ap + i*1024 + ks*32);
      b[i] = *(const short8*)(Bp + i*1024 + ks*32);
    }
#pragma unroll
    for (int i = 0; i < 4; i++)
#pragma unroll
      for (int j = 0; j < 4; j++)
        acc[i][j] = __builtin_amdgcn_mfma_f32_16x16x32_bf16(a[i], b[j], acc[i][j], 0, 0, 0);
  }
#pragma unroll
  for (int j = 0; j < 4; j++){
    const int n = n0 + wn*64 + j*16 + lrow;
    const float wo = Wo[n];
#pragma unroll
    for (int i = 0; i < 4; i++)
#pragma unroll
      for (int r = 0; r < 4; r++){
        const long m = m0 + wm*64 + i*16 + lq*4 + r;
        const float sig = 1.f / (1.f + __expf(-acc[i][j][r]));
        wprod[m*512 + n] = f2h(sig * bf2f(aggh[m*512 + n]) * wo);
      }
  }
}

// ---------------- fused: logits = aggh@Waa/0.7 -> online softmax -> out ----------------
// block = 128 rows, wave = 32 rows x 128 cols; 4 N-steps in-block; no logits materialization.
__global__ __launch_bounds__(256) void gemm_final(
    const u16* __restrict__ A, const u16* __restrict__ Bt,
    const u16* __restrict__ wprod, const float* __restrict__ sku,
    const float* __restrict__ wWo, float* __restrict__ outp)
{
  const int t = threadIdx.x, wv = t >> 6, ln = t & 63;
  const long m0 = (long)blockIdx.x * 128;
  const int lrow = ln & 15, lq = ln >> 4;
  const float inv_t = 1.0f / 0.7f;
  const u16* Ap = A + (m0 + wv*32 + lrow)*512 + lq*8;

  float m_run[2][4], s_run[2][4], t_run[2][4];
#pragma unroll
  for (int i = 0; i < 2; i++)
#pragma unroll
    for (int r = 0; r < 4; r++){ m_run[i][r] = -1e30f; s_run[i][r] = 0.f; t_run[i][r] = 0.f; }

#pragma unroll 1
  for (int ns = 0; ns < 4; ns++){
    const int n0 = ns * 128;
    const u16* Bp = Bt + (long)(n0 + lrow)*512 + lq*8;

    short8 a[2], b[8];
#pragma unroll
    for (int i = 0; i < 2; i++) a[i] = *(const short8*)(Ap + i*8192);
#pragma unroll
    for (int j = 0; j < 8; j++) b[j] = *(const short8*)(Bp + j*8192);
    f32x4 acc[2][8] = {};
#pragma unroll 1
    for (int ks = 1; ks < 16; ks++){
      short8 na[2], nb[8];
#pragma unroll
      for (int i = 0; i < 2; i++) na[i] = *(const short8*)(Ap + i*8192 + ks*32);
#pragma unroll
      for (int j = 0; j < 8; j++) nb[j] = *(const short8*)(Bp + j*8192 + ks*32);
#pragma unroll
      for (int i = 0; i < 2; i++)
#pragma unroll
        for (int j = 0; j < 8; j++)
          acc[i][j] = __builtin_amdgcn_mfma_f32_16x16x32_bf16(a[i], b[j], acc[i][j], 0, 0, 0);
#pragma unroll
      for (int i = 0; i < 2; i++) a[i] = na[i];
#pragma unroll
      for (int j = 0; j < 8; j++) b[j] = nb[j];
    }
#pragma unroll
    for (int i = 0; i < 2; i++)
#pragma unroll
      for (int j = 0; j < 8; j++)
        acc[i][j] = __builtin_amdgcn_mfma_f32_16x16x32_bf16(a[i], b[j], acc[i][j], 0, 0, 0);

    // online-softmax merge for this 128-col slab
#pragma unroll
    for (int i = 0; i < 2; i++)
#pragma unroll
      for (int r = 0; r < 4; r++){
        float mt = -1e30f;
#pragma unroll
        for (int j = 0; j < 8; j++) mt = fmaxf(mt, acc[i][j][r]);
        mt = bfly_max16(mt) * inv_t;
        const float mnew = fmaxf(m_run[i][r], mt);
        const long row = m0 + wv*32 + i*16 + lq*4 + r;
        float sp = 0.f, tp = 0.f;
#pragma unroll
        for (int j = 0; j < 8; j++){
          const float e = __expf(acc[i][j][r]*inv_t - mnew);
          sp += e;
          tp += e * h2f(wprod[row*512 + n0 + j*16 + lrow]);
        }
        sp = bfly_sum16(sp);
        tp = bfly_sum16(tp);
        const float sc = __expf(m_run[i][r] - mnew);
        s_run[i][r] = s_run[i][r]*sc + sp;
        t_run[i][r] = t_run[i][r]*sc + tp;
        m_run[i][r] = mnew;
      }
  }

  const f32x4 wl = *(const f32x4*)&wWo[lrow*4];
#pragma unroll
  for (int i = 0; i < 2; i++)
#pragma unroll
    for (int r = 0; r < 4; r++){
      const long row = m0 + wv*32 + i*16 + lq*4 + r;
      const f32x4 sv = *(const f32x4*)&sku[row*64 + lrow*4];
      float d = sv.x*wl.x + sv.y*wl.y + sv.z*wl.z + sv.w*wl.w;
      d = bfly_sum16(d);
      if (lrow == 0) outp[row] = t_run[i][r] / s_run[i][r] + d;
    }
}

__global__ void ws_too_small(float* o, float v){ o[(long)blockIdx.x*256 + threadIdx.x] = v; }

extern "C" void kernel_launch(void* const* d_in, const int* in_sizes, int n_in,
                              void* d_out, int out_size, void* d_ws, size_t ws_size,
                              hipStream_t stream)
{
  const float* inputs = (const float*)d_in[0];
  const float* sku    = (const float*)d_in[1];
  const float* deltas = (const float*)d_in[2];
  const float* ln_g   = (const float*)d_in[3];
  const float* ln_b   = (const float*)d_in[4];
  const float* attnw  = (const float*)d_in[5];
  const float* Wh     = (const float*)d_in[6];
  const float* Wah    = (const float*)d_in[7];
  const float* Waa    = (const float*)d_in[8];
  const float* Wb     = (const float*)d_in[9];
  const float* Wa     = (const float*)d_in[10];
  const float* Wo     = (const float*)d_in[11];
  float* outp = (float*)d_out;

  const size_t OFF_CPS  = 0;                      // 2048
  const size_t OFF_WWO  = 2048;                   // 256
  const size_t OFF_WAHT = 4096;                   // 524288
  const size_t OFF_WAAT = OFF_WAHT + 524288;
  const size_t OFF_WBT  = OFF_WAAT + 524288;
  const size_t OFF_WHT  = OFF_WBT  + 65536;
  const size_t OFF_SKUB = OFF_WHT  + 32768;
  const size_t OFF_AGG  = OFF_SKUB + (size_t)CHUNK*64*2;
  const size_t OFF_AGH  = OFF_AGG  + (size_t)CHUNK*512*2;
  const size_t NEED     = OFF_AGH  + (size_t)CHUNK*512*2;   // ~137 MB

  if (ws_size < NEED){
    hipLaunchKernelGGL(ws_too_small, dim3(B_TOT/256), dim3(256), 0, stream,
                       outp, -(float)(ws_size >> 20));
    return;
  }

  char* ws = (char*)d_ws;
  float* cps  = (float*)(ws + OFF_CPS);
  float* wWo  = (float*)(ws + OFF_WWO);
  u16* WahT   = (u16*)(ws + OFF_WAHT);
  u16* WaaT   = (u16*)(ws + OFF_WAAT);
  u16* WbT    = (u16*)(ws + OFF_WBT);
  u16* WhT    = (u16*)(ws + OFF_WHT);
  u16* skub   = (u16*)(ws + OFF_SKUB);
  u16* agg    = (u16*)(ws + OFF_AGG);
  u16* aggh   = (u16*)(ws + OFF_AGH);
  u16* wprod  = agg;   // agg dead after gemm_mish; reuse slot for wprod

  hipLaunchKernelGGL(prep_small, dim3(1), dim3(128), 0, stream, deltas, Wa, Wo, cps, wWo);
  hipLaunchKernelGGL(prep_convert, dim3(2240), dim3(256), 0, stream,
                     Wah, Waa, Wb, Wh, WahT, WaaT, WbT, WhT);

  for (int ch = 0; ch < B_TOT / CHUNK; ch++){
    const float* in_c  = inputs + (size_t)ch * CHUNK * 16;
    const float* sku_c = sku    + (size_t)ch * CHUNK * 64;
    float* out_c       = outp   + (size_t)ch * CHUNK;

    hipLaunchKernelGGL(stage1_kernel, dim3(CHUNK/16), dim3(256), 0, stream,
                       in_c, sku_c, ln_g, ln_b, attnw, cps, WhT, agg, skub);
    hipLaunchKernelGGL(gemm_mish, dim3(CHUNK/128*4), dim3(256), 0, stream, agg, WahT, aggh);
    hipLaunchKernelGGL(gemm_beta, dim3(CHUNK/128*4), dim3(256), 0, stream,
                       skub, WbT, aggh, Wo, wprod);
    hipLaunchKernelGGL(gemm_final, dim3(CHUNK/128), dim3(256), 0, stream,
                       aggh, WaaT, wprod, sku_c, wWo, out_c);
  }
}

// Round 4
// 672.605 us; speedup vs baseline: 1.3169x; 1.3169x over previous
//
#include <hip/hip_runtime.h>
#include <hip/hip_fp16.h>
#include <stdint.h>

#define B_TOT 131072
#define CHUNK 65536
#define NH 16
#define NC 32
#define HIDD 512

typedef unsigned short u16;
typedef __attribute__((ext_vector_type(8))) short short8;
typedef __attribute__((ext_vector_type(4))) float f32x4;
typedef __attribute__((ext_vector_type(4))) int i32x4;

#define GLLDS(g, l) __builtin_amdgcn_global_load_lds((const __attribute__((address_space(1))) unsigned int*)(g), (__attribute__((address_space(3))) unsigned int*)(l), 16, 0, 0)

__device__ __forceinline__ u16 f2bf(float x){
  unsigned u = __float_as_uint(x);
  u += 0x7fffu + ((u >> 16) & 1u);
  return (u16)(u >> 16);
}
__device__ __forceinline__ float bf2f(u16 b){ return __uint_as_float(((unsigned)b) << 16); }
__device__ __forceinline__ u16 f2h(float x){ __half h = __float2half(x); return *(u16*)&h; }
__device__ __forceinline__ float h2f(u16 b){ __half h; *(u16*)&h = b; return __half2float(h); }
// mish(x) = x*tanh(softplus(x)); tanh(log(1+e^x)) == (u^2-1)/(u^2+1), u = 1+e^x (exact identity)
__device__ __forceinline__ float mishf(float x){
  float e = __expf(fminf(x, 30.f));
  float u = 1.f + e;
  float u2 = u * u;
  return x * (u2 - 1.f) / (u2 + 1.f);
}

// ---------------- prep kernels ----------------
__global__ void prep_small(const float* __restrict__ deltas, const float* __restrict__ Wa,
                           const float* __restrict__ Wo, float* __restrict__ cps, float* __restrict__ wWo)
{
  const int t = threadIdx.x;
  if (t < NH){
    float cum[NC];
    float run = 0.f;
#pragma unroll
    for (int c = 0; c < NC; c++){
      float d = deltas[t*NC + c];
      float sp = (d > 20.f) ? d : log1pf(__expf(d));
      run += sp; cum[c] = run;
    }
    float s = 365.0f / run;
#pragma unroll
    for (int c = 0; c < NC; c++) cps[t*NC + c] = cum[c] * s;
  } else if (t >= 64 && t < 128){
    const int k = t - 64;
    float s = 0.f;
    for (int n = 0; n < HIDD; n++) s += Wa[k*HIDD + n] * Wo[n];
    wWo[k] = s;
  }
}

__global__ void prep_convert(const float* __restrict__ Wah, const float* __restrict__ Waa,
                             const float* __restrict__ Wb, const float* __restrict__ Wh,
                             u16* __restrict__ WahT, u16* __restrict__ WaaT,
                             u16* __restrict__ WbT, u16* __restrict__ WhT)
{
  int i = blockIdx.x * 256 + threadIdx.x;
  if (i < 262144){ int n = i >> 9, k = i & 511; WahT[i] = f2bf(Wah[k*512 + n]); return; }
  i -= 262144;
  if (i < 262144){ int n = i >> 9, k = i & 511; WaaT[i] = f2bf(Waa[k*512 + n]); return; }
  i -= 262144;
  if (i < 32768){ int n = i >> 6, k = i & 63; WbT[i] = f2bf(Wb[k*512 + n]); return; }
  i -= 32768;
  if (i < 16384){ int h = i >> 10, r = i & 1023, d = r >> 5, c = r & 31;
                  WhT[i] = f2bf(Wh[h*1024 + c*32 + d]); return; }
}

// ---------------- stage 1: feats -> LN -> softmax -> einsum(MFMA) -> mish; also skub + skd ----------------
__global__ __launch_bounds__(256) void stage1_kernel(
    const float* __restrict__ inputs, const float* __restrict__ sku,
    const float* __restrict__ ln_g, const float* __restrict__ ln_b,
    const float* __restrict__ attnw, const float* __restrict__ cps,
    const float* __restrict__ wWo, const u16* __restrict__ WhT,
    u16* __restrict__ agg, u16* __restrict__ skub, float* __restrict__ skd)
{
  __shared__ __align__(16) float in_l[256];
  __shared__ __align__(16) float cps_l[512];
  __shared__ __align__(16) float gam_l[512];
  __shared__ __align__(16) float bet_l[512];
  __shared__ float aw_l[16];
  __shared__ __align__(16) u16 at_l[16*16*32];   // [h][b16][c32]
  __shared__ __align__(16) u16 ot_l[16*512];     // [b16][512]

  const int t = threadIdx.x;
  const int ln = t & 63;
  const long bb = (long)blockIdx.x * 16;

  in_l[t] = inputs[bb*16 + t];
  cps_l[t] = cps[t];       cps_l[t+256] = cps[t+256];
  gam_l[t] = ln_g[t];      gam_l[t+256] = ln_g[t+256];
  bet_l[t] = ln_b[t];      bet_l[t+256] = ln_b[t+256];
  if (t < 16) aw_l[t] = attnw[t];
  { // sku -> bf16 (16 rows x 64) + skd = sku . wWo per row
    const f32x4 sv = *(const f32x4*)&sku[bb*64 + t*4];
    unsigned lo = (unsigned)f2bf(sv.x) | ((unsigned)f2bf(sv.y) << 16);
    unsigned hi = (unsigned)f2bf(sv.z) | ((unsigned)f2bf(sv.w) << 16);
    unsigned long long v = (unsigned long long)lo | ((unsigned long long)hi << 32);
    *(unsigned long long*)&skub[bb*64 + t*4] = v;
    const f32x4 wv4 = *(const f32x4*)&wWo[(ln & 15)*4];
    float pd = sv.x*wv4.x + sv.y*wv4.y + sv.z*wv4.z + sv.w*wv4.w;
#pragma unroll
    for (int s = 1; s < 16; s <<= 1) pd += __shfl_xor(pd, s);
    if ((ln & 15) == 0) skd[bb + (t >> 4)] = pd;
  }
  __syncthreads();

  const int h = t >> 4, bi = t & 15;
  const float x = in_l[bi*16 + h];
  float nrm[NC], pw[NC];
  float s1 = 0.f;
#pragma unroll
  for (int c = 0; c < NC; c++){ float f = fmaxf(x - cps_l[h*NC + c], 0.f); nrm[c] = f; s1 += f; }
  const float mu = s1 * (1.f/NC);
  float s2 = 0.f;
#pragma unroll
  for (int c = 0; c < NC; c++){ float d = nrm[c] - mu; s2 += d*d; }
  const float rs = rsqrtf(s2 * (1.f/NC) + 1e-3f);
  const float aw = aw_l[h] * (1.0f/0.7f);
  float lmax = -1e30f;
#pragma unroll
  for (int c = 0; c < NC; c++){
    float nv = (nrm[c] - mu) * rs * gam_l[h*NC + c] + bet_l[h*NC + c];
    nrm[c] = nv;
    lmax = fmaxf(lmax, nv * aw);
  }
  float ps = 0.f;
#pragma unroll
  for (int c = 0; c < NC; c++){ float p = __expf(nrm[c]*aw - lmax); pw[c] = p; ps += p; }
  const float invs = 1.f / ps;
#pragma unroll
  for (int c = 0; c < NC; c += 2){
    unsigned pk = (unsigned)f2bf(nrm[c]*pw[c]*invs) | ((unsigned)f2bf(nrm[c+1]*pw[c+1]*invs) << 16);
    *(unsigned*)&at_l[h*512 + bi*32 + c] = pk;
  }
  __syncthreads();

  const int wv = t >> 6;
  const int lrow = ln & 15, lq = ln >> 4;
#pragma unroll
  for (int q = 0; q < 4; q++){
    const int hh = wv*4 + q;
    short8 af  = *(const short8*)&at_l[hh*512 + lrow*32 + lq*8];
    short8 bf0 = *(const short8*)&WhT[hh*1024 + lrow*32 + lq*8];
    short8 bf1 = *(const short8*)&WhT[hh*1024 + (16 + lrow)*32 + lq*8];
    f32x4 acc0 = {0.f,0.f,0.f,0.f}, acc1 = {0.f,0.f,0.f,0.f};
    acc0 = __builtin_amdgcn_mfma_f32_16x16x32_bf16(af, bf0, acc0, 0, 0, 0);
    acc1 = __builtin_amdgcn_mfma_f32_16x16x32_bf16(af, bf1, acc1, 0, 0, 0);
#pragma unroll
    for (int r = 0; r < 4; r++){
      const int br = lq*4 + r;
      ot_l[br*512 + hh*32 + lrow]      = f2bf(mishf(acc0[r]));
      ot_l[br*512 + hh*32 + 16 + lrow] = f2bf(mishf(acc1[r]));
    }
  }
  __syncthreads();
  {
    const int row = t >> 4, c16 = t & 15;
    const i32x4* src = (const i32x4*)&ot_l[row*512 + c16*32];
    i32x4* dst = (i32x4*)&agg[(bb + row)*512 + c16*32];
#pragma unroll
    for (int j = 0; j < 4; j++) dst[j] = src[j];
  }
}

// ---------------- GEMM (round-2 proven skeleton): [M x 512] @ Bt[512 x 512] -> mish -> bf16 ----------------
__global__ __launch_bounds__(256, 2) void gemm_mish(
    const u16* __restrict__ A, const u16* __restrict__ Bt, u16* __restrict__ outp)
{
  __shared__ __align__(16) u16 As[2][128*32];
  __shared__ __align__(16) u16 Bs[2][128*32];
  const int t = threadIdx.x, wv = t >> 6, ln = t & 63;
  const long m0 = (long)(blockIdx.x >> 2) * 128;
  const int n0 = (blockIdx.x & 3) * 128;
  const int lrow = ln & 15, lq = ln >> 4;
  const int wm = wv >> 1, wn = wv & 1;

  auto stage = [&](int buf, int kt){
#pragma unroll
    for (int p = 0; p < 2; p++){
      const int chunk = p*256 + wv*64 + ln;
      const int mm = chunk >> 2, kc = chunk & 3;
      GLLDS(&A[(m0 + mm)*512 + kt + kc*8],        &As[buf][(p*256 + wv*64)*8]);
      GLLDS(&Bt[(long)(n0 + mm)*512 + kt + kc*8], &Bs[buf][(p*256 + wv*64)*8]);
    }
  };

  f32x4 acc[4][4] = {};
  stage(0, 0);
  for (int ks = 0; ks < 16; ks++){
    const int cur = ks & 1;
    __syncthreads();
    if (ks + 1 < 16) stage(cur ^ 1, (ks + 1)*32);
    short8 a[4], b[4];
#pragma unroll
    for (int i = 0; i < 4; i++){
      a[i] = *(const short8*)&As[cur][(wm*64 + i*16 + lrow)*32 + lq*8];
      b[i] = *(const short8*)&Bs[cur][(wn*64 + i*16 + lrow)*32 + lq*8];
    }
#pragma unroll
    for (int i = 0; i < 4; i++)
#pragma unroll
      for (int j = 0; j < 4; j++)
        acc[i][j] = __builtin_amdgcn_mfma_f32_16x16x32_bf16(a[i], b[j], acc[i][j], 0, 0, 0);
  }
#pragma unroll
  for (int i = 0; i < 4; i++)
#pragma unroll
    for (int j = 0; j < 4; j++)
#pragma unroll
      for (int r = 0; r < 4; r++){
        const long m = m0 + wm*64 + i*16 + lq*4 + r;
        const int n = n0 + wn*64 + j*16 + lrow;
        outp[m*512 + n] = f2bf(mishf(acc[i][j][r]));
      }
}

// ---------------- beta GEMM K=64 + wprod epilogue: wprod = sigmoid(skub@Wb) * aggh * Wo (fp16) ----------------
__global__ __launch_bounds__(256, 2) void gemm_wprod(
    const u16* __restrict__ A, const u16* __restrict__ Bt, const u16* __restrict__ aggh,
    const float* __restrict__ Wo, u16* __restrict__ wp)
{
  __shared__ __align__(16) u16 As[2][128*32];
  __shared__ __align__(16) u16 Bs[2][128*32];
  const int t = threadIdx.x, wv = t >> 6, ln = t & 63;
  const long m0 = (long)(blockIdx.x >> 2) * 128;
  const int n0 = (blockIdx.x & 3) * 128;
  const int lrow = ln & 15, lq = ln >> 4;
  const int wm = wv >> 1, wn = wv & 1;

  auto stage = [&](int buf, int kt){
#pragma unroll
    for (int p = 0; p < 2; p++){
      const int chunk = p*256 + wv*64 + ln;
      const int mm = chunk >> 2, kc = chunk & 3;
      GLLDS(&A[(m0 + mm)*64 + kt + kc*8],  &As[buf][(p*256 + wv*64)*8]);
      GLLDS(&Bt[(n0 + mm)*64 + kt + kc*8], &Bs[buf][(p*256 + wv*64)*8]);
    }
  };

  f32x4 acc[4][4] = {};
  stage(0, 0);
  for (int ks = 0; ks < 2; ks++){
    const int cur = ks & 1;
    __syncthreads();
    if (ks + 1 < 2) stage(cur ^ 1, (ks + 1)*32);
    short8 a[4], b[4];
#pragma unroll
    for (int i = 0; i < 4; i++){
      a[i] = *(const short8*)&As[cur][(wm*64 + i*16 + lrow)*32 + lq*8];
      b[i] = *(const short8*)&Bs[cur][(wn*64 + i*16 + lrow)*32 + lq*8];
    }
#pragma unroll
    for (int i = 0; i < 4; i++)
#pragma unroll
      for (int j = 0; j < 4; j++)
        acc[i][j] = __builtin_amdgcn_mfma_f32_16x16x32_bf16(a[i], b[j], acc[i][j], 0, 0, 0);
  }
#pragma unroll
  for (int j = 0; j < 4; j++){
    const int n = n0 + wn*64 + j*16 + lrow;
    const float wo = Wo[n];
#pragma unroll
    for (int i = 0; i < 4; i++)
#pragma unroll
      for (int r = 0; r < 4; r++){
        const long m = m0 + wm*64 + i*16 + lq*4 + r;
        const float sig = 1.f / (1.f + __expf(-acc[i][j][r]));
        wp[m*512 + n] = f2h(sig * bf2f(aggh[m*512 + n]) * wo);
      }
  }
}

// ---------------- fused: logits = aggh@Waa -> softmax(/0.7) -> out = sum(attn*wprod) + skd ----------------
// block = 64 rows x full N=512; 8 waves, each 64m x 64n (acc[4][4]); LDS-staged A+B (round-2 skeleton).
__global__ __launch_bounds__(512, 3) void p2_fused(
    const u16* __restrict__ A, const u16* __restrict__ Bt,
    const u16* __restrict__ wprod, const float* __restrict__ skd,
    float* __restrict__ outp)
{
  __shared__ __align__(16) u16 As[2][64*32];    // 8 KB total
  __shared__ __align__(16) u16 Bs[2][512*32];   // 64 KB total
  const int t = threadIdx.x, wv = t >> 6, ln = t & 63;
  const int lrow = ln & 15, lq = ln >> 4;
  const long m0 = (long)blockIdx.x * 64;

  auto stageA = [&](int buf, int kt){
    if (t < 256) GLLDS(&A[(m0 + (t >> 2))*512 + kt + (t & 3)*8], &As[buf][t*8]);
  };
  auto stageB = [&](int buf, int kt){
#pragma unroll
    for (int p = 0; p < 4; p++){
      const int idx = p*512 + t;
      GLLDS(&Bt[(long)(idx >> 2)*512 + kt + (idx & 3)*8], &Bs[buf][idx*8]);
    }
  };

  f32x4 acc[4][4] = {};
  stageA(0, 0); stageB(0, 0);
  for (int ks = 0; ks < 16; ks++){
    const int cur = ks & 1;
    __syncthreads();
    if (ks + 1 < 16){ stageA(cur ^ 1, (ks + 1)*32); stageB(cur ^ 1, (ks + 1)*32); }
    short8 a[4], b[4];
#pragma unroll
    for (int i = 0; i < 4; i++){
      a[i] = *(const short8*)&As[cur][(i*16 + lrow)*32 + lq*8];
      b[i] = *(const short8*)&Bs[cur][(wv*64 + i*16 + lrow)*32 + lq*8];
    }
#pragma unroll
    for (int i = 0; i < 4; i++)
#pragma unroll
      for (int j = 0; j < 4; j++)
        acc[i][j] = __builtin_amdgcn_mfma_f32_16x16x32_bf16(a[i], b[j], acc[i][j], 0, 0, 0);
  }

  // ---- fused softmax + weighted-sum epilogue; stats overlay in dead A-buffer (6 KB <= 8 KB) ----
  __syncthreads();
  float* mxs = (float*)&As[0][0];   // [64][8]
  float* sss = mxs + 512;           // [64][8]
  float* tts = sss + 512;           // [64][8]
  const float inv_t = 1.0f / 0.7f;

#pragma unroll
  for (int i = 0; i < 4; i++)
#pragma unroll
    for (int r = 0; r < 4; r++){
      float tm = acc[i][0][r];
#pragma unroll
      for (int j = 1; j < 4; j++) tm = fmaxf(tm, acc[i][j][r]);
#pragma unroll
      for (int s = 1; s < 16; s <<= 1) tm = fmaxf(tm, __shfl_xor(tm, s));
      if (lrow == 0) mxs[(i*16 + lq*4 + r)*8 + wv] = tm;
    }
  __syncthreads();
#pragma unroll
  for (int i = 0; i < 4; i++)
#pragma unroll
    for (int r = 0; r < 4; r++){
      const int row = i*16 + lq*4 + r;
      float gm = mxs[row*8 + 0];
#pragma unroll
      for (int s = 1; s < 8; s++) gm = fmaxf(gm, mxs[row*8 + s]);
      float sp = 0.f, tp = 0.f;
#pragma unroll
      for (int j = 0; j < 4; j++){
        const int col = wv*64 + j*16 + lrow;
        const float e = __expf((acc[i][j][r] - gm) * inv_t);
        sp += e;
        tp += e * h2f(wprod[(m0 + row)*512 + col]);
      }
#pragma unroll
      for (int s = 1; s < 16; s <<= 1){ sp += __shfl_xor(sp, s); tp += __shfl_xor(tp, s); }
      if (lrow == 0){ sss[row*8 + wv] = sp; tts[row*8 + wv] = tp; }
    }
  __syncthreads();
  if (t < 64){
    float S = 0.f, T = 0.f;
#pragma unroll
    for (int s = 0; s < 8; s++){ S += sss[t*8 + s]; T += tts[t*8 + s]; }
    outp[m0 + t] = T / S + skd[m0 + t];
  }
}

__global__ void ws_too_small(float* o, float v){ o[(long)blockIdx.x*256 + threadIdx.x] = v; }

extern "C" void kernel_launch(void* const* d_in, const int* in_sizes, int n_in,
                              void* d_out, int out_size, void* d_ws, size_t ws_size,
                              hipStream_t stream)
{
  const float* inputs = (const float*)d_in[0];
  const float* sku    = (const float*)d_in[1];
  const float* deltas = (const float*)d_in[2];
  const float* ln_g   = (const float*)d_in[3];
  const float* ln_b   = (const float*)d_in[4];
  const float* attnw  = (const float*)d_in[5];
  const float* Wh     = (const float*)d_in[6];
  const float* Wah    = (const float*)d_in[7];
  const float* Waa    = (const float*)d_in[8];
  const float* Wb     = (const float*)d_in[9];
  const float* Wa     = (const float*)d_in[10];
  const float* Wo     = (const float*)d_in[11];
  float* outp = (float*)d_out;

  const size_t OFF_CPS  = 0;
  const size_t OFF_WWO  = 2048;
  const size_t OFF_WAHT = 4096;
  const size_t OFF_WAAT = OFF_WAHT + 524288;
  const size_t OFF_WBT  = OFF_WAAT + 524288;
  const size_t OFF_WHT  = OFF_WBT  + 65536;
  const size_t OFF_SKUB = OFF_WHT  + 32768;
  const size_t OFF_SKD  = OFF_SKUB + (size_t)CHUNK*64*2;
  const size_t OFF_AGG  = OFF_SKD  + (size_t)CHUNK*4;
  const size_t OFF_AGH  = OFF_AGG  + (size_t)CHUNK*512*2;
  const size_t NEED     = OFF_AGH  + (size_t)CHUNK*512*2;   // ~138 MB

  if (ws_size < NEED){
    hipLaunchKernelGGL(ws_too_small, dim3(B_TOT/256), dim3(256), 0, stream,
                       outp, -(float)(ws_size >> 20));
    return;
  }

  char* ws = (char*)d_ws;
  float* cps  = (float*)(ws + OFF_CPS);
  float* wWo  = (float*)(ws + OFF_WWO);
  u16* WahT   = (u16*)(ws + OFF_WAHT);
  u16* WaaT   = (u16*)(ws + OFF_WAAT);
  u16* WbT    = (u16*)(ws + OFF_WBT);
  u16* WhT    = (u16*)(ws + OFF_WHT);
  u16* skub   = (u16*)(ws + OFF_SKUB);
  float* skd  = (float*)(ws + OFF_SKD);
  u16* agg    = (u16*)(ws + OFF_AGG);
  u16* aggh   = (u16*)(ws + OFF_AGH);
  u16* wprod  = agg;   // agg dead after gemm_mish; reuse slot

  hipLaunchKernelGGL(prep_small, dim3(1), dim3(128), 0, stream, deltas, Wa, Wo, cps, wWo);
  hipLaunchKernelGGL(prep_convert, dim3(2240), dim3(256), 0, stream,
                     Wah, Waa, Wb, Wh, WahT, WaaT, WbT, WhT);

  for (int ch = 0; ch < B_TOT / CHUNK; ch++){
    const float* in_c  = inputs + (size_t)ch * CHUNK * 16;
    const float* sku_c = sku    + (size_t)ch * CHUNK * 64;
    float* out_c       = outp   + (size_t)ch * CHUNK;

    hipLaunchKernelGGL(stage1_kernel, dim3(CHUNK/16), dim3(256), 0, stream,
                       in_c, sku_c, ln_g, ln_b, attnw, cps, wWo, WhT, agg, skub, skd);
    hipLaunchKernelGGL(gemm_mish, dim3(CHUNK/128*4), dim3(256), 0, stream, agg, WahT, aggh);
    hipLaunchKernelGGL(gemm_wprod, dim3(CHUNK/128*4), dim3(256), 0, stream,
                       skub, WbT, aggh, Wo, wprod);
    hipLaunchKernelGGL(p2_fused, dim3(CHUNK/64), dim3(512), 0, stream,
                       aggh, WaaT, wprod, skd, out_c);
  }
}

// Round 6
// 591.743 us; speedup vs baseline: 1.4968x; 1.1367x over previous
//
#include <hip/hip_runtime.h>
#include <hip/hip_fp16.h>
#include <stdint.h>

#define B_TOT 131072
#define CHUNK 65536
#define NH 16
#define NC 32
#define HIDD 512

typedef unsigned short u16;
typedef __attribute__((ext_vector_type(8))) short short8;
typedef __attribute__((ext_vector_type(4))) float f32x4;
typedef __attribute__((ext_vector_type(4))) int i32x4;

#define GLLDS(g, l) __builtin_amdgcn_global_load_lds((const __attribute__((address_space(1))) unsigned int*)(g), (__attribute__((address_space(3))) unsigned int*)(l), 16, 0, 0)

__device__ __forceinline__ u16 f2bf(float x){
  unsigned u = __float_as_uint(x);
  u += 0x7fffu + ((u >> 16) & 1u);
  return (u16)(u >> 16);
}
__device__ __forceinline__ float bf2f(u16 b){ return __uint_as_float(((unsigned)b) << 16); }
__device__ __forceinline__ u16 f2h(float x){ __half h = __float2half(x); return *(u16*)&h; }
__device__ __forceinline__ float h2f(u16 b){ __half h; *(u16*)&h = b; return __half2float(h); }
// mish(x) = x*tanh(softplus(x)); tanh(log(1+e^x)) == (u^2-1)/(u^2+1), u = 1+e^x (exact identity)
__device__ __forceinline__ float mishf(float x){
  float e = __expf(fminf(x, 30.f));
  float u = 1.f + e;
  float u2 = u * u;
  return x * (u2 - 1.f) / (u2 + 1.f);
}

// ---------------- prep kernels ----------------
__global__ void prep_small(const float* __restrict__ deltas, const float* __restrict__ Wa,
                           const float* __restrict__ Wo, float* __restrict__ cps, float* __restrict__ wWo)
{
  const int t = threadIdx.x;
  if (t < NH){
    float cum[NC];
    float run = 0.f;
#pragma unroll
    for (int c = 0; c < NC; c++){
      float d = deltas[t*NC + c];
      float sp = (d > 20.f) ? d : log1pf(__expf(d));
      run += sp; cum[c] = run;
    }
    float s = 365.0f / run;
#pragma unroll
    for (int c = 0; c < NC; c++) cps[t*NC + c] = cum[c] * s;
  } else if (t >= 64 && t < 128){
    const int k = t - 64;
    float s = 0.f;
    for (int n = 0; n < HIDD; n++) s += Wa[k*HIDD + n] * Wo[n];
    wWo[k] = s;
  }
}

__global__ void prep_convert(const float* __restrict__ Wah, const float* __restrict__ Waa,
                             const float* __restrict__ Wb, const float* __restrict__ Wh,
                             u16* __restrict__ WahT, u16* __restrict__ WaaT,
                             u16* __restrict__ WbT, u16* __restrict__ WhT)
{
  int i = blockIdx.x * 256 + threadIdx.x;
  if (i < 262144){ int n = i >> 9, k = i & 511; WahT[i] = f2bf(Wah[k*512 + n]); return; }
  i -= 262144;
  if (i < 262144){ int n = i >> 9, k = i & 511; WaaT[i] = f2bf(Waa[k*512 + n]); return; }
  i -= 262144;
  if (i < 32768){ int n = i >> 6, k = i & 63; WbT[i] = f2bf(Wb[k*512 + n]); return; }
  i -= 32768;
  if (i < 16384){ int h = i >> 10, r = i & 1023, d = r >> 5, c = r & 31;
                  WhT[i] = f2bf(Wh[h*1024 + c*32 + d]); return; }
}

// ---------------- stage 1: feats -> LN -> softmax -> einsum(MFMA) -> mish; also skub + skd ----------------
__global__ __launch_bounds__(256) void stage1_kernel(
    const float* __restrict__ inputs, const float* __restrict__ sku,
    const float* __restrict__ ln_g, const float* __restrict__ ln_b,
    const float* __restrict__ attnw, const float* __restrict__ cps,
    const float* __restrict__ wWo, const u16* __restrict__ WhT,
    u16* __restrict__ agg, u16* __restrict__ skub, float* __restrict__ skd)
{
  __shared__ __align__(16) float in_l[256];
  __shared__ __align__(16) float cps_l[512];
  __shared__ __align__(16) float gam_l[512];
  __shared__ __align__(16) float bet_l[512];
  __shared__ float aw_l[16];
  __shared__ __align__(16) u16 at_l[16*16*32];   // [h][b16][c32]
  __shared__ __align__(16) u16 ot_l[16*512];     // [b16][512]

  const int t = threadIdx.x;
  const int ln = t & 63;
  const long bb = (long)blockIdx.x * 16;

  in_l[t] = inputs[bb*16 + t];
  cps_l[t] = cps[t];       cps_l[t+256] = cps[t+256];
  gam_l[t] = ln_g[t];      gam_l[t+256] = ln_g[t+256];
  bet_l[t] = ln_b[t];      bet_l[t+256] = ln_b[t+256];
  if (t < 16) aw_l[t] = attnw[t];
  { // sku -> bf16 (16 rows x 64) + skd = sku . wWo per row
    const f32x4 sv = *(const f32x4*)&sku[bb*64 + t*4];
    unsigned lo = (unsigned)f2bf(sv.x) | ((unsigned)f2bf(sv.y) << 16);
    unsigned hi = (unsigned)f2bf(sv.z) | ((unsigned)f2bf(sv.w) << 16);
    unsigned long long v = (unsigned long long)lo | ((unsigned long long)hi << 32);
    *(unsigned long long*)&skub[bb*64 + t*4] = v;
    const f32x4 wv4 = *(const f32x4*)&wWo[(ln & 15)*4];
    float pd = sv.x*wv4.x + sv.y*wv4.y + sv.z*wv4.z + sv.w*wv4.w;
#pragma unroll
    for (int s = 1; s < 16; s <<= 1) pd += __shfl_xor(pd, s);
    if ((ln & 15) == 0) skd[bb + (t >> 4)] = pd;
  }
  __syncthreads();

  const int h = t >> 4, bi = t & 15;
  const float x = in_l[bi*16 + h];
  float nrm[NC], pw[NC];
  float s1 = 0.f;
#pragma unroll
  for (int c = 0; c < NC; c++){ float f = fmaxf(x - cps_l[h*NC + c], 0.f); nrm[c] = f; s1 += f; }
  const float mu = s1 * (1.f/NC);
  float s2 = 0.f;
#pragma unroll
  for (int c = 0; c < NC; c++){ float d = nrm[c] - mu; s2 += d*d; }
  const float rs = rsqrtf(s2 * (1.f/NC) + 1e-3f);
  const float aw = aw_l[h] * (1.0f/0.7f);
  float lmax = -1e30f;
#pragma unroll
  for (int c = 0; c < NC; c++){
    float nv = (nrm[c] - mu) * rs * gam_l[h*NC + c] + bet_l[h*NC + c];
    nrm[c] = nv;
    lmax = fmaxf(lmax, nv * aw);
  }
  float ps = 0.f;
#pragma unroll
  for (int c = 0; c < NC; c++){ float p = __expf(nrm[c]*aw - lmax); pw[c] = p; ps += p; }
  const float invs = 1.f / ps;
#pragma unroll
  for (int c = 0; c < NC; c += 2){
    unsigned pk = (unsigned)f2bf(nrm[c]*pw[c]*invs) | ((unsigned)f2bf(nrm[c+1]*pw[c+1]*invs) << 16);
    *(unsigned*)&at_l[h*512 + bi*32 + c] = pk;
  }
  __syncthreads();

  const int wv = t >> 6;
  const int lrow = ln & 15, lq = ln >> 4;
#pragma unroll
  for (int q = 0; q < 4; q++){
    const int hh = wv*4 + q;
    short8 af  = *(const short8*)&at_l[hh*512 + lrow*32 + lq*8];
    short8 bf0 = *(const short8*)&WhT[hh*1024 + lrow*32 + lq*8];
    short8 bf1 = *(const short8*)&WhT[hh*1024 + (16 + lrow)*32 + lq*8];
    f32x4 acc0 = {0.f,0.f,0.f,0.f}, acc1 = {0.f,0.f,0.f,0.f};
    acc0 = __builtin_amdgcn_mfma_f32_16x16x32_bf16(af, bf0, acc0, 0, 0, 0);
    acc1 = __builtin_amdgcn_mfma_f32_16x16x32_bf16(af, bf1, acc1, 0, 0, 0);
#pragma unroll
    for (int r = 0; r < 4; r++){
      const int br = lq*4 + r;
      ot_l[br*512 + hh*32 + lrow]      = f2bf(mishf(acc0[r]));
      ot_l[br*512 + hh*32 + 16 + lrow] = f2bf(mishf(acc1[r]));
    }
  }
  __syncthreads();
  {
    const int row = t >> 4, c16 = t & 15;
    const i32x4* src = (const i32x4*)&ot_l[row*512 + c16*32];
    i32x4* dst = (i32x4*)&agg[(bb + row)*512 + c16*32];
#pragma unroll
    for (int j = 0; j < 4; j++) dst[j] = src[j];
  }
}

// ---------------- GEMM (round-2 skeleton + XCD swizzle + LDS bank-XOR swizzle) ----------------
// [M x KD] bf16 @ Bt[512 n][KD k] -> epilogue -> 16-bit [M x 512]
// EPI: 0 = mish -> bf16 ; 1 = raw logit -> fp16 ; 2 = sigmoid*aux*Wo -> fp16
template<int KD, int EPI>
__global__ __launch_bounds__(256, 3) void gemm_k(
    const u16* __restrict__ A, const u16* __restrict__ Bt,
    const u16* __restrict__ aux, const float* __restrict__ Wo,
    u16* __restrict__ outp)
{
  __shared__ __align__(16) u16 As[2][128*32];
  __shared__ __align__(16) u16 Bs[2][128*32];
  const int t = threadIdx.x, wv = t >> 6, ln = t & 63;
  const int g = blockIdx.x;
  // XCD swizzle: blocks g, g+8, g+16, g+24 share one A-stripe and one XCD (round-robin g%8)
  const int m_idx = (g & 7) + ((g >> 5) << 3);
  const int n_idx = (g >> 3) & 3;
  const long m0 = (long)m_idx * 128;
  const int n0 = n_idx * 128;
  const int lrow = ln & 15, lq = ln >> 4;
  const int wm = wv >> 1, wn = wv & 1;

  // Stage with k-chunk XOR swizzle: LDS slot (mm, kc) holds global chunk kc^((mm>>1)&3).
  auto stage = [&](int buf, int kt){
#pragma unroll
    for (int p = 0; p < 2; p++){
      const int chunk = p*256 + wv*64 + ln;
      const int mm = chunk >> 2, kc = chunk & 3;
      const int kcl = kc ^ ((mm >> 1) & 3);
      GLLDS(&A[(m0 + mm)*KD + kt + kcl*8],        &As[buf][(p*256 + wv*64)*8]);
      GLLDS(&Bt[(long)(n0 + mm)*KD + kt + kcl*8], &Bs[buf][(p*256 + wv*64)*8]);
    }
  };

  f32x4 acc[4][4] = {};
  stage(0, 0);
  const int NK = KD / 32;
  for (int ks = 0; ks < NK; ks++){
    const int cur = ks & 1;
    __syncthreads();
    if (ks + 1 < NK) stage(cur ^ 1, (ks + 1)*32);
    short8 a[4], b[4];
#pragma unroll
    for (int i = 0; i < 4; i++){
      const int ra = wm*64 + i*16 + lrow;
      const int rb = wn*64 + i*16 + lrow;
      const int lqa = lq ^ ((ra >> 1) & 3);
      const int lqb = lq ^ ((rb >> 1) & 3);
      a[i] = *(const short8*)&As[cur][ra*32 + lqa*8];
      b[i] = *(const short8*)&Bs[cur][rb*32 + lqb*8];
    }
#pragma unroll
    for (int i = 0; i < 4; i++)
#pragma unroll
      for (int j = 0; j < 4; j++)
        acc[i][j] = __builtin_amdgcn_mfma_f32_16x16x32_bf16(a[i], b[j], acc[i][j], 0, 0, 0);
  }
#pragma unroll
  for (int j = 0; j < 4; j++){
    const int n = n0 + wn*64 + j*16 + lrow;
    float wo = 0.f;
    if (EPI == 2) wo = Wo[n];
#pragma unroll
    for (int i = 0; i < 4; i++){
#pragma unroll
      for (int r = 0; r < 4; r++){
        const long m = m0 + wm*64 + i*16 + lq*4 + r;
        const float v = acc[i][j][r];
        u16 ob;
        if (EPI == 0)      ob = f2bf(mishf(v));
        else if (EPI == 1) ob = f2h(v);
        else {
          const float sig = 1.f / (1.f + __expf(-v));
          ob = f2h(sig * bf2f(aux[m*512 + n]) * wo);
        }
        outp[m*512 + n] = ob;
      }
    }
  }
}

// ---------------- final: softmax(logits/0.7) -> out = sum(attn * wprod) + skd ----------------
__global__ __launch_bounds__(256) void final_kernel(
    const u16* __restrict__ logits, const u16* __restrict__ wprod,
    const float* __restrict__ skd, float* __restrict__ outp)
{
  const int t = threadIdx.x;
  const int wv = t >> 6, ln = t & 63;
  const long rbase = (long)blockIdx.x * 32 + wv*8;
  const float inv_t = 1.0f / 0.7f;
#pragma unroll 1
  for (int j = 0; j < 8; j++){
    const long row = rbase + j;
    i32x4 lv = *(const i32x4*)&logits[row*512 + ln*8];
    const u16* lp = (const u16*)&lv;
    float l[8];
#pragma unroll
    for (int q = 0; q < 8; q++) l[q] = h2f(lp[q]) * inv_t;
    float mx = l[0];
#pragma unroll
    for (int q = 1; q < 8; q++) mx = fmaxf(mx, l[q]);
#pragma unroll
    for (int s = 1; s < 64; s <<= 1) mx = fmaxf(mx, __shfl_xor(mx, s));
    i32x4 wvv = *(const i32x4*)&wprod[row*512 + ln*8];
    const u16* wp = (const u16*)&wvv;
    float ps = 0.f, ts = 0.f;
#pragma unroll
    for (int q = 0; q < 8; q++){
      const float e = __expf(l[q] - mx);
      ps += e;
      ts += e * h2f(wp[q]);
    }
#pragma unroll
    for (int s = 1; s < 64; s <<= 1){ ps += __shfl_xor(ps, s); ts += __shfl_xor(ts, s); }
    if (ln == 0) outp[row] = ts / ps + skd[row];
  }
}

__global__ void ws_too_small(float* o, float v){ o[(long)blockIdx.x*256 + threadIdx.x] = v; }

extern "C" void kernel_launch(void* const* d_in, const int* in_sizes, int n_in,
                              void* d_out, int out_size, void* d_ws, size_t ws_size,
                              hipStream_t stream)
{
  const float* inputs = (const float*)d_in[0];
  const float* sku    = (const float*)d_in[1];
  const float* deltas = (const float*)d_in[2];
  const float* ln_g   = (const float*)d_in[3];
  const float* ln_b   = (const float*)d_in[4];
  const float* attnw  = (const float*)d_in[5];
  const float* Wh     = (const float*)d_in[6];
  const float* Wah    = (const float*)d_in[7];
  const float* Waa    = (const float*)d_in[8];
  const float* Wb     = (const float*)d_in[9];
  const float* Wa     = (const float*)d_in[10];
  const float* Wo     = (const float*)d_in[11];
  float* outp = (float*)d_out;

  const size_t OFF_CPS  = 0;
  const size_t OFF_WWO  = 2048;
  const size_t OFF_WAHT = 4096;
  const size_t OFF_WAAT = OFF_WAHT + 524288;
  const size_t OFF_WBT  = OFF_WAAT + 524288;
  const size_t OFF_WHT  = OFF_WBT  + 65536;
  const size_t OFF_SKUB = OFF_WHT  + 32768;
  const size_t OFF_SKD  = OFF_SKUB + (size_t)CHUNK*64*2;
  const size_t OFF_AGG  = OFF_SKD  + (size_t)CHUNK*4;
  const size_t OFF_AGH  = OFF_AGG  + (size_t)CHUNK*512*2;
  const size_t OFF_LOG  = OFF_AGH  + (size_t)CHUNK*512*2;
  const size_t NEED     = OFF_LOG  + (size_t)CHUNK*512*2;   // ~202 MB

  if (ws_size < NEED){
    hipLaunchKernelGGL(ws_too_small, dim3(B_TOT/256), dim3(256), 0, stream,
                       outp, -(float)(ws_size >> 20));
    return;
  }

  char* ws = (char*)d_ws;
  float* cps  = (float*)(ws + OFF_CPS);
  float* wWo  = (float*)(ws + OFF_WWO);
  u16* WahT   = (u16*)(ws + OFF_WAHT);
  u16* WaaT   = (u16*)(ws + OFF_WAAT);
  u16* WbT    = (u16*)(ws + OFF_WBT);
  u16* WhT    = (u16*)(ws + OFF_WHT);
  u16* skub   = (u16*)(ws + OFF_SKUB);
  float* skd  = (float*)(ws + OFF_SKD);
  u16* agg    = (u16*)(ws + OFF_AGG);
  u16* aggh   = (u16*)(ws + OFF_AGH);
  u16* logits = (u16*)(ws + OFF_LOG);
  u16* wprod  = agg;   // agg dead after gemm_mish; reuse slot

  hipLaunchKernelGGL(prep_small, dim3(1), dim3(128), 0, stream, deltas, Wa, Wo, cps, wWo);
  hipLaunchKernelGGL(prep_convert, dim3(2240), dim3(256), 0, stream,
                     Wah, Waa, Wb, Wh, WahT, WaaT, WbT, WhT);

  for (int ch = 0; ch < B_TOT / CHUNK; ch++){
    const float* in_c  = inputs + (size_t)ch * CHUNK * 16;
    const float* sku_c = sku    + (size_t)ch * CHUNK * 64;
    float* out_c       = outp   + (size_t)ch * CHUNK;

    hipLaunchKernelGGL(stage1_kernel, dim3(CHUNK/16), dim3(256), 0, stream,
                       in_c, sku_c, ln_g, ln_b, attnw, cps, wWo, WhT, agg, skub, skd);
    hipLaunchKernelGGL((gemm_k<512,0>), dim3(CHUNK/128*4), dim3(256), 0, stream,
                       agg, WahT, (const u16*)nullptr, (const float*)nullptr, aggh);
    hipLaunchKernelGGL((gemm_k<64,2>),  dim3(CHUNK/128*4), dim3(256), 0, stream,
                       skub, WbT, aggh, Wo, wprod);
    hipLaunchKernelGGL((gemm_k<512,1>), dim3(CHUNK/128*4), dim3(256), 0, stream,
                       aggh, WaaT, (const u16*)nullptr, (const float*)nullptr, logits);
    hipLaunchKernelGGL(final_kernel, dim3(CHUNK/32), dim3(256), 0, stream,
                       logits, wprod, skd, out_c);
  }
}

// Round 7
// 553.758 us; speedup vs baseline: 1.5995x; 1.0686x over previous
//
#include <hip/hip_runtime.h>
#include <hip/hip_fp16.h>
#include <stdint.h>

#define B_TOT 131072
#define CHUNK 65536
#define NH 16
#define NC 32
#define HIDD 512

typedef unsigned short u16;
typedef __attribute__((ext_vector_type(8))) short short8;
typedef __attribute__((ext_vector_type(4))) float f32x4;
typedef __attribute__((ext_vector_type(4))) int i32x4;

#define GLLDS(g, l) __builtin_amdgcn_global_load_lds((const __attribute__((address_space(1))) unsigned int*)(g), (__attribute__((address_space(3))) unsigned int*)(l), 16, 0, 0)

__device__ __forceinline__ u16 f2bf(float x){
  unsigned u = __float_as_uint(x);
  u += 0x7fffu + ((u >> 16) & 1u);
  return (u16)(u >> 16);
}
__device__ __forceinline__ float bf2f(u16 b){ return __uint_as_float(((unsigned)b) << 16); }
__device__ __forceinline__ u16 f2h(float x){ __half h = __float2half(x); return *(u16*)&h; }
__device__ __forceinline__ float h2f(u16 b){ __half h; *(u16*)&h = b; return __half2float(h); }
// mish(x) = x*tanh(softplus(x)); tanh(log(1+e^x)) == (u^2-1)/(u^2+1), u = 1+e^x (exact identity)
__device__ __forceinline__ float mishf(float x){
  float e = __expf(fminf(x, 30.f));
  float u = 1.f + e;
  float u2 = u * u;
  return x * (u2 - 1.f) / (u2 + 1.f);
}

// ---------------- prep kernels ----------------
__global__ void prep_small(const float* __restrict__ deltas, const float* __restrict__ Wa,
                           const float* __restrict__ Wo, float* __restrict__ cps, float* __restrict__ wWo)
{
  const int t = threadIdx.x;
  if (t < NH){
    float cum[NC];
    float run = 0.f;
#pragma unroll
    for (int c = 0; c < NC; c++){
      float d = deltas[t*NC + c];
      float sp = (d > 20.f) ? d : log1pf(__expf(d));
      run += sp; cum[c] = run;
    }
    float s = 365.0f / run;
#pragma unroll
    for (int c = 0; c < NC; c++) cps[t*NC + c] = cum[c] * s;
  } else if (t >= 64 && t < 128){
    const int k = t - 64;
    float s = 0.f;
    for (int n = 0; n < HIDD; n++) s += Wa[k*HIDD + n] * Wo[n];
    wWo[k] = s;
  }
}

__global__ void prep_convert(const float* __restrict__ Wah, const float* __restrict__ Waa,
                             const float* __restrict__ Wb, const float* __restrict__ Wh,
                             u16* __restrict__ WahT, u16* __restrict__ WaaT,
                             u16* __restrict__ WbT, u16* __restrict__ WhT)
{
  int i = blockIdx.x * 256 + threadIdx.x;
  if (i < 262144){ int n = i >> 9, k = i & 511; WahT[i] = f2bf(Wah[k*512 + n]); return; }
  i -= 262144;
  if (i < 262144){ int n = i >> 9, k = i & 511; WaaT[i] = f2bf(Waa[k*512 + n]); return; }
  i -= 262144;
  if (i < 32768){ int n = i >> 6, k = i & 63; WbT[i] = f2bf(Wb[k*512 + n]); return; }
  i -= 32768;
  if (i < 16384){ int h = i >> 10, r = i & 1023, d = r >> 5, c = r & 31;
                  WhT[i] = f2bf(Wh[h*1024 + c*32 + d]); return; }
}

// ---------------- stage 1: feats -> LN -> softmax -> einsum(MFMA) -> mish; also skub + skd ----------------
__global__ __launch_bounds__(256) void stage1_kernel(
    const float* __restrict__ inputs, const float* __restrict__ sku,
    const float* __restrict__ ln_g, const float* __restrict__ ln_b,
    const float* __restrict__ attnw, const float* __restrict__ cps,
    const float* __restrict__ wWo, const u16* __restrict__ WhT,
    u16* __restrict__ agg, u16* __restrict__ skub, float* __restrict__ skd)
{
  __shared__ __align__(16) float in_l[256];
  __shared__ __align__(16) float cps_l[512];
  __shared__ __align__(16) float gam_l[512];
  __shared__ __align__(16) float bet_l[512];
  __shared__ float aw_l[16];
  __shared__ __align__(16) u16 at_l[16*16*32];   // [h][b16][c32]
  __shared__ __align__(16) u16 ot_l[16*512];     // [b16][512]

  const int t = threadIdx.x;
  const int ln = t & 63;
  const long bb = (long)blockIdx.x * 16;

  in_l[t] = inputs[bb*16 + t];
  cps_l[t] = cps[t];       cps_l[t+256] = cps[t+256];
  gam_l[t] = ln_g[t];      gam_l[t+256] = ln_g[t+256];
  bet_l[t] = ln_b[t];      bet_l[t+256] = ln_b[t+256];
  if (t < 16) aw_l[t] = attnw[t];
  { // sku -> bf16 (16 rows x 64) + skd = sku . wWo per row
    const f32x4 sv = *(const f32x4*)&sku[bb*64 + t*4];
    unsigned lo = (unsigned)f2bf(sv.x) | ((unsigned)f2bf(sv.y) << 16);
    unsigned hi = (unsigned)f2bf(sv.z) | ((unsigned)f2bf(sv.w) << 16);
    unsigned long long v = (unsigned long long)lo | ((unsigned long long)hi << 32);
    *(unsigned long long*)&skub[bb*64 + t*4] = v;
    const f32x4 wv4 = *(const f32x4*)&wWo[(ln & 15)*4];
    float pd = sv.x*wv4.x + sv.y*wv4.y + sv.z*wv4.z + sv.w*wv4.w;
#pragma unroll
    for (int s = 1; s < 16; s <<= 1) pd += __shfl_xor(pd, s);
    if ((ln & 15) == 0) skd[bb + (t >> 4)] = pd;
  }
  __syncthreads();

  const int h = t >> 4, bi = t & 15;
  const float x = in_l[bi*16 + h];
  float nrm[NC], pw[NC];
  float s1 = 0.f;
#pragma unroll
  for (int c = 0; c < NC; c++){ float f = fmaxf(x - cps_l[h*NC + c], 0.f); nrm[c] = f; s1 += f; }
  const float mu = s1 * (1.f/NC);
  float s2 = 0.f;
#pragma unroll
  for (int c = 0; c < NC; c++){ float d = nrm[c] - mu; s2 += d*d; }
  const float rs = rsqrtf(s2 * (1.f/NC) + 1e-3f);
  const float aw = aw_l[h] * (1.0f/0.7f);
  float lmax = -1e30f;
#pragma unroll
  for (int c = 0; c < NC; c++){
    float nv = (nrm[c] - mu) * rs * gam_l[h*NC + c] + bet_l[h*NC + c];
    nrm[c] = nv;
    lmax = fmaxf(lmax, nv * aw);
  }
  float ps = 0.f;
#pragma unroll
  for (int c = 0; c < NC; c++){ float p = __expf(nrm[c]*aw - lmax); pw[c] = p; ps += p; }
  const float invs = 1.f / ps;
#pragma unroll
  for (int c = 0; c < NC; c += 2){
    unsigned pk = (unsigned)f2bf(nrm[c]*pw[c]*invs) | ((unsigned)f2bf(nrm[c+1]*pw[c+1]*invs) << 16);
    *(unsigned*)&at_l[h*512 + bi*32 + c] = pk;
  }
  __syncthreads();

  const int wv = t >> 6;
  const int lrow = ln & 15, lq = ln >> 4;
#pragma unroll
  for (int q = 0; q < 4; q++){
    const int hh = wv*4 + q;
    short8 af  = *(const short8*)&at_l[hh*512 + lrow*32 + lq*8];
    short8 bf0 = *(const short8*)&WhT[hh*1024 + lrow*32 + lq*8];
    short8 bf1 = *(const short8*)&WhT[hh*1024 + (16 + lrow)*32 + lq*8];
    f32x4 acc0 = {0.f,0.f,0.f,0.f}, acc1 = {0.f,0.f,0.f,0.f};
    acc0 = __builtin_amdgcn_mfma_f32_16x16x32_bf16(af, bf0, acc0, 0, 0, 0);
    acc1 = __builtin_amdgcn_mfma_f32_16x16x32_bf16(af, bf1, acc1, 0, 0, 0);
#pragma unroll
    for (int r = 0; r < 4; r++){
      const int br = lq*4 + r;
      ot_l[br*512 + hh*32 + lrow]      = f2bf(mishf(acc0[r]));
      ot_l[br*512 + hh*32 + 16 + lrow] = f2bf(mishf(acc1[r]));
    }
  }
  __syncthreads();
  {
    const int row = t >> 4, c16 = t & 15;
    const i32x4* src = (const i32x4*)&ot_l[row*512 + c16*32];
    i32x4* dst = (i32x4*)&agg[(bb + row)*512 + c16*32];
#pragma unroll
    for (int j = 0; j < 4; j++) dst[j] = src[j];
  }
}

// ---------------- gemm_bw: K=64 (128x128 skeleton): bw = f2h(sigmoid(skub@WbT) * Wo[n]) ----------------
__global__ __launch_bounds__(256, 3) void gemm_bw(
    const u16* __restrict__ A, const u16* __restrict__ Bt,
    const float* __restrict__ Wo, u16* __restrict__ bw)
{
  __shared__ __align__(16) u16 As[2][128*32];
  __shared__ __align__(16) u16 Bs[2][128*32];
  const int t = threadIdx.x, wv = t >> 6, ln = t & 63;
  const int g = blockIdx.x;
  const int m_idx = (g & 7) + ((g >> 5) << 3);
  const int n_idx = (g >> 3) & 3;
  const long m0 = (long)m_idx * 128;
  const int n0 = n_idx * 128;
  const int lrow = ln & 15, lq = ln >> 4;
  const int wm = wv >> 1, wn = wv & 1;

  auto stage = [&](int buf, int kt){
#pragma unroll
    for (int p = 0; p < 2; p++){
      const int chunk = p*256 + wv*64 + ln;
      const int mm = chunk >> 2, kc = chunk & 3;
      const int kcl = kc ^ ((mm >> 1) & 3);
      GLLDS(&A[(m0 + mm)*64 + kt + kcl*8],  &As[buf][(p*256 + wv*64)*8]);
      GLLDS(&Bt[(n0 + mm)*64 + kt + kcl*8], &Bs[buf][(p*256 + wv*64)*8]);
    }
  };

  f32x4 acc[4][4] = {};
  stage(0, 0);
  for (int ks = 0; ks < 2; ks++){
    const int cur = ks & 1;
    __syncthreads();
    if (ks + 1 < 2) stage(cur ^ 1, (ks + 1)*32);
    short8 a[4], b[4];
#pragma unroll
    for (int i = 0; i < 4; i++){
      const int ra = wm*64 + i*16 + lrow;
      const int rb = wn*64 + i*16 + lrow;
      const int lqa = lq ^ ((ra >> 1) & 3);
      const int lqb = lq ^ ((rb >> 1) & 3);
      a[i] = *(const short8*)&As[cur][ra*32 + lqa*8];
      b[i] = *(const short8*)&Bs[cur][rb*32 + lqb*8];
    }
#pragma unroll
    for (int i = 0; i < 4; i++)
#pragma unroll
      for (int j = 0; j < 4; j++)
        acc[i][j] = __builtin_amdgcn_mfma_f32_16x16x32_bf16(a[i], b[j], acc[i][j], 0, 0, 0);
  }
#pragma unroll
  for (int j = 0; j < 4; j++){
    const int n = n0 + wn*64 + j*16 + lrow;
    const float wo = Wo[n];
#pragma unroll
    for (int i = 0; i < 4; i++){
#pragma unroll
      for (int r = 0; r < 4; r++){
        const long m = m0 + wm*64 + i*16 + lq*4 + r;
        const float sig = 1.f / (1.f + __expf(-acc[i][j][r]));
        bw[m*512 + n] = f2h(sig * wo);
      }
    }
  }
}

// ---------------- gemm_mishw: 128x512 tile, K=512. aggh = mish(agg@WahT); wprod = aggh*bw (in-place over agg) ----------------
__global__ __launch_bounds__(512, 2) void gemm_mishw(
    const u16* __restrict__ A, const u16* __restrict__ Bt,
    const u16* __restrict__ bw, u16* __restrict__ aggh, u16* __restrict__ wp)
{
  __shared__ __align__(16) u16 As[2][128*32];   // 16 KB
  __shared__ __align__(16) u16 Bs[2][512*32];   // 64 KB
  const int t = threadIdx.x, wv = t >> 6, ln = t & 63;
  const int lrow = ln & 15, lq = ln >> 4;
  const int rh = wv >> 2, cq = wv & 3;
  const long m0 = (long)blockIdx.x * 128;

  auto stageA = [&](int buf, int kt){
    const int mm = t >> 2, kc = t & 3;
    const int kcl = kc ^ ((mm >> 1) & 3);
    GLLDS(&A[(m0 + mm)*512 + kt + kcl*8], &As[buf][t*8]);
  };
  auto stageB = [&](int buf, int kt){
#pragma unroll
    for (int p = 0; p < 4; p++){
      const int idx = p*512 + t;
      const int mm = idx >> 2, kc = idx & 3;
      const int kcl = kc ^ ((mm >> 1) & 3);
      GLLDS(&Bt[(long)mm*512 + kt + kcl*8], &Bs[buf][idx*8]);
    }
  };

  f32x4 acc[4][8] = {};
  stageA(0, 0); stageB(0, 0);
  for (int ks = 0; ks < 16; ks++){
    const int cur = ks & 1;
    __syncthreads();
    if (ks + 1 < 16){ stageA(cur ^ 1, (ks + 1)*32); stageB(cur ^ 1, (ks + 1)*32); }
    short8 a[4], b[8];
#pragma unroll
    for (int i = 0; i < 4; i++){
      const int ra = rh*64 + i*16 + lrow;
      const int lqa = lq ^ ((ra >> 1) & 3);
      a[i] = *(const short8*)&As[cur][ra*32 + lqa*8];
    }
#pragma unroll
    for (int j = 0; j < 8; j++){
      const int rb = cq*128 + j*16 + lrow;
      const int lqb = lq ^ ((rb >> 1) & 3);
      b[j] = *(const short8*)&Bs[cur][rb*32 + lqb*8];
    }
#pragma unroll
    for (int i = 0; i < 4; i++)
#pragma unroll
      for (int j = 0; j < 8; j++)
        acc[i][j] = __builtin_amdgcn_mfma_f32_16x16x32_bf16(a[i], b[j], acc[i][j], 0, 0, 0);
  }
  // all GLLDS reads of agg drained by the ks=15 barrier -> in-place wp write is safe
#pragma unroll
  for (int i = 0; i < 4; i++){
#pragma unroll
    for (int j = 0; j < 8; j++){
#pragma unroll
      for (int r = 0; r < 4; r++){
        const long m = m0 + rh*64 + i*16 + lq*4 + r;
        const int n = cq*128 + j*16 + lrow;
        const float h = mishf(acc[i][j][r]);
        aggh[m*512 + n] = f2bf(h);
        wp[m*512 + n]   = f2h(h * h2f(bw[m*512 + n]));
      }
    }
  }
}

// ---------------- mega2: 128x512 tile, K=512. logits = aggh@WaaT -> softmax(/0.7) -> out = sum(attn*wprod)+skd ----------------
__global__ __launch_bounds__(512, 2) void mega2(
    const u16* __restrict__ A, const u16* __restrict__ Bt,
    const u16* __restrict__ wprod, const float* __restrict__ skd,
    float* __restrict__ outp)
{
  __shared__ __align__(16) u16 As[2][128*32];
  __shared__ __align__(16) u16 Bs[2][512*32];
  const int t = threadIdx.x, wv = t >> 6, ln = t & 63;
  const int lrow = ln & 15, lq = ln >> 4;
  const int rh = wv >> 2, cq = wv & 3;
  const long m0 = (long)blockIdx.x * 128;

  auto stageA = [&](int buf, int kt){
    const int mm = t >> 2, kc = t & 3;
    const int kcl = kc ^ ((mm >> 1) & 3);
    GLLDS(&A[(m0 + mm)*512 + kt + kcl*8], &As[buf][t*8]);
  };
  auto stageB = [&](int buf, int kt){
#pragma unroll
    for (int p = 0; p < 4; p++){
      const int idx = p*512 + t;
      const int mm = idx >> 2, kc = idx & 3;
      const int kcl = kc ^ ((mm >> 1) & 3);
      GLLDS(&Bt[(long)mm*512 + kt + kcl*8], &Bs[buf][idx*8]);
    }
  };

  f32x4 acc[4][8] = {};
  stageA(0, 0); stageB(0, 0);
  for (int ks = 0; ks < 16; ks++){
    const int cur = ks & 1;
    __syncthreads();
    if (ks + 1 < 16){ stageA(cur ^ 1, (ks + 1)*32); stageB(cur ^ 1, (ks + 1)*32); }
    short8 a[4], b[8];
#pragma unroll
    for (int i = 0; i < 4; i++){
      const int ra = rh*64 + i*16 + lrow;
      const int lqa = lq ^ ((ra >> 1) & 3);
      a[i] = *(const short8*)&As[cur][ra*32 + lqa*8];
    }
#pragma unroll
    for (int j = 0; j < 8; j++){
      const int rb = cq*128 + j*16 + lrow;
      const int lqb = lq ^ ((rb >> 1) & 3);
      b[j] = *(const short8*)&Bs[cur][rb*32 + lqb*8];
    }
#pragma unroll
    for (int i = 0; i < 4; i++)
#pragma unroll
      for (int j = 0; j < 8; j++)
        acc[i][j] = __builtin_amdgcn_mfma_f32_16x16x32_bf16(a[i], b[j], acc[i][j], 0, 0, 0);
  }

  // ---- softmax + weighted-sum epilogue; stats overlay in dead Bs buffer ----
  __syncthreads();
  float* mxs = (float*)&Bs[0][0];   // [128][4]
  float* sss = mxs + 512;           // [128][4]
  float* tts = sss + 512;           // [128][4]
  const float inv_t = 1.0f / 0.7f;

#pragma unroll
  for (int i = 0; i < 4; i++){
#pragma unroll
    for (int r = 0; r < 4; r++){
      float tm = acc[i][0][r];
#pragma unroll
      for (int j = 1; j < 8; j++) tm = fmaxf(tm, acc[i][j][r]);
#pragma unroll
      for (int s = 1; s < 16; s <<= 1) tm = fmaxf(tm, __shfl_xor(tm, s));
      if (lrow == 0) mxs[(rh*64 + i*16 + lq*4 + r)*4 + cq] = tm;
    }
  }
  __syncthreads();
#pragma unroll
  for (int i = 0; i < 4; i++){
#pragma unroll
    for (int r = 0; r < 4; r++){
      const int row = rh*64 + i*16 + lq*4 + r;
      const float gm = fmaxf(fmaxf(mxs[row*4+0], mxs[row*4+1]),
                             fmaxf(mxs[row*4+2], mxs[row*4+3]));
      float sp = 0.f, tp = 0.f;
#pragma unroll
      for (int j = 0; j < 8; j++){
        const float e = __expf((acc[i][j][r] - gm) * inv_t);
        sp += e;
        tp += e * h2f(wprod[(m0 + row)*512 + cq*128 + j*16 + lrow]);
      }
#pragma unroll
      for (int s = 1; s < 16; s <<= 1){ sp += __shfl_xor(sp, s); tp += __shfl_xor(tp, s); }
      if (lrow == 0){ sss[row*4 + cq] = sp; tts[row*4 + cq] = tp; }
    }
  }
  __syncthreads();
  if (t < 128){
    const float S = sss[t*4] + sss[t*4+1] + sss[t*4+2] + sss[t*4+3];
    const float T = tts[t*4] + tts[t*4+1] + tts[t*4+2] + tts[t*4+3];
    outp[m0 + t] = T / S + skd[m0 + t];
  }
}

__global__ void ws_too_small(float* o, float v){ o[(long)blockIdx.x*256 + threadIdx.x] = v; }

extern "C" void kernel_launch(void* const* d_in, const int* in_sizes, int n_in,
                              void* d_out, int out_size, void* d_ws, size_t ws_size,
                              hipStream_t stream)
{
  const float* inputs = (const float*)d_in[0];
  const float* sku    = (const float*)d_in[1];
  const float* deltas = (const float*)d_in[2];
  const float* ln_g   = (const float*)d_in[3];
  const float* ln_b   = (const float*)d_in[4];
  const float* attnw  = (const float*)d_in[5];
  const float* Wh     = (const float*)d_in[6];
  const float* Wah    = (const float*)d_in[7];
  const float* Waa    = (const float*)d_in[8];
  const float* Wb     = (const float*)d_in[9];
  const float* Wa     = (const float*)d_in[10];
  const float* Wo     = (const float*)d_in[11];
  float* outp = (float*)d_out;

  const size_t OFF_CPS  = 0;
  const size_t OFF_WWO  = 2048;
  const size_t OFF_WAHT = 4096;
  const size_t OFF_WAAT = OFF_WAHT + 524288;
  const size_t OFF_WBT  = OFF_WAAT + 524288;
  const size_t OFF_WHT  = OFF_WBT  + 65536;
  const size_t OFF_SKUB = OFF_WHT  + 32768;
  const size_t OFF_SKD  = OFF_SKUB + (size_t)CHUNK*64*2;
  const size_t OFF_AGG  = OFF_SKD  + (size_t)CHUNK*4;      // doubles as wprod (in-place)
  const size_t OFF_BW   = OFF_AGG  + (size_t)CHUNK*512*2;
  const size_t OFF_AGH  = OFF_BW   + (size_t)CHUNK*512*2;
  const size_t NEED     = OFF_AGH  + (size_t)CHUNK*512*2;  // ~211 MB

  if (ws_size < NEED){
    hipLaunchKernelGGL(ws_too_small, dim3(B_TOT/256), dim3(256), 0, stream,
                       outp, -(float)(ws_size >> 20));
    return;
  }

  char* ws = (char*)d_ws;
  float* cps  = (float*)(ws + OFF_CPS);
  float* wWo  = (float*)(ws + OFF_WWO);
  u16* WahT   = (u16*)(ws + OFF_WAHT);
  u16* WaaT   = (u16*)(ws + OFF_WAAT);
  u16* WbT    = (u16*)(ws + OFF_WBT);
  u16* WhT    = (u16*)(ws + OFF_WHT);
  u16* skub   = (u16*)(ws + OFF_SKUB);
  float* skd  = (float*)(ws + OFF_SKD);
  u16* agg    = (u16*)(ws + OFF_AGG);
  u16* bw     = (u16*)(ws + OFF_BW);
  u16* aggh   = (u16*)(ws + OFF_AGH);
  u16* wprod  = agg;   // written in-place by gemm_mishw after it consumes agg

  hipLaunchKernelGGL(prep_small, dim3(1), dim3(128), 0, stream, deltas, Wa, Wo, cps, wWo);
  hipLaunchKernelGGL(prep_convert, dim3(2240), dim3(256), 0, stream,
                     Wah, Waa, Wb, Wh, WahT, WaaT, WbT, WhT);

  for (int ch = 0; ch < B_TOT / CHUNK; ch++){
    const float* in_c  = inputs + (size_t)ch * CHUNK * 16;
    const float* sku_c = sku    + (size_t)ch * CHUNK * 64;
    float* out_c       = outp   + (size_t)ch * CHUNK;

    hipLaunchKernelGGL(stage1_kernel, dim3(CHUNK/16), dim3(256), 0, stream,
                       in_c, sku_c, ln_g, ln_b, attnw, cps, wWo, WhT, agg, skub, skd);
    hipLaunchKernelGGL(gemm_bw, dim3(CHUNK/128*4), dim3(256), 0, stream,
                       skub, WbT, Wo, bw);
    hipLaunchKernelGGL(gemm_mishw, dim3(CHUNK/128), dim3(512), 0, stream,
                       agg, WahT, bw, aggh, wprod);
    hipLaunchKernelGGL(mega2, dim3(CHUNK/128), dim3(512), 0, stream,
                       aggh, WaaT, wprod, skd, out_c);
  }
}

// Round 8
// 520.490 us; speedup vs baseline: 1.7017x; 1.0639x over previous
//
#include <hip/hip_runtime.h>
#include <hip/hip_fp16.h>
#include <stdint.h>

#define B_TOT 131072
#define CHUNK 65536
#define NH 16
#define NC 32
#define HIDD 512

typedef unsigned short u16;
typedef __attribute__((ext_vector_type(8))) short short8;
typedef __attribute__((ext_vector_type(4))) float f32x4;
typedef __attribute__((ext_vector_type(4))) int i32x4;

#define GLLDS(g, l) __builtin_amdgcn_global_load_lds((const __attribute__((address_space(1))) unsigned int*)(g), (__attribute__((address_space(3))) unsigned int*)(l), 16, 0, 0)

__device__ __forceinline__ u16 f2bf(float x){
  unsigned u = __float_as_uint(x);
  u += 0x7fffu + ((u >> 16) & 1u);
  return (u16)(u >> 16);
}
__device__ __forceinline__ float bf2f(u16 b){ return __uint_as_float(((unsigned)b) << 16); }
__device__ __forceinline__ u16 f2h(float x){ __half h = __float2half(x); return *(u16*)&h; }
__device__ __forceinline__ float h2f(u16 b){ __half h; *(u16*)&h = b; return __half2float(h); }
// mish(x) = x*tanh(softplus(x)); tanh(log(1+e^x)) == (u^2-1)/(u^2+1), u = 1+e^x (exact identity)
__device__ __forceinline__ float mishf(float x){
  float e = __expf(fminf(x, 30.f));
  float u = 1.f + e;
  float u2 = u * u;
  return x * (u2 - 1.f) / (u2 + 1.f);
}

// ---------------- prep kernels ----------------
__global__ void prep_small(const float* __restrict__ deltas, const float* __restrict__ Wa,
                           const float* __restrict__ Wo, float* __restrict__ cps, float* __restrict__ wWo)
{
  const int t = threadIdx.x;
  if (t < NH){
    float cum[NC];
    float run = 0.f;
#pragma unroll
    for (int c = 0; c < NC; c++){
      float d = deltas[t*NC + c];
      float sp = (d > 20.f) ? d : log1pf(__expf(d));
      run += sp; cum[c] = run;
    }
    float s = 365.0f / run;
#pragma unroll
    for (int c = 0; c < NC; c++) cps[t*NC + c] = cum[c] * s;
  } else if (t >= 64 && t < 128){
    const int k = t - 64;
    float s = 0.f;
    for (int n = 0; n < HIDD; n++) s += Wa[k*HIDD + n] * Wo[n];
    wWo[k] = s;
  }
}

__global__ void prep_convert(const float* __restrict__ Wah, const float* __restrict__ Waa,
                             const float* __restrict__ Wb, const float* __restrict__ Wh,
                             u16* __restrict__ WahT, u16* __restrict__ WaaT,
                             u16* __restrict__ WbT, u16* __restrict__ WhT)
{
  int i = blockIdx.x * 256 + threadIdx.x;
  if (i < 262144){ int n = i >> 9, k = i & 511; WahT[i] = f2bf(Wah[k*512 + n]); return; }
  i -= 262144;
  if (i < 262144){ int n = i >> 9, k = i & 511; WaaT[i] = f2bf(Waa[k*512 + n]); return; }
  i -= 262144;
  if (i < 32768){ int n = i >> 6, k = i & 63; WbT[i] = f2bf(Wb[k*512 + n]); return; }
  i -= 32768;
  if (i < 16384){ int h = i >> 10, r = i & 1023, d = r >> 5, c = r & 31;
                  WhT[i] = f2bf(Wh[h*1024 + c*32 + d]); return; }
}

// ---------------- stage 1: feats -> LN -> softmax -> einsum(MFMA) -> mish; also skub + skd ----------------
__global__ __launch_bounds__(256) void stage1_kernel(
    const float* __restrict__ inputs, const float* __restrict__ sku,
    const float* __restrict__ ln_g, const float* __restrict__ ln_b,
    const float* __restrict__ attnw, const float* __restrict__ cps,
    const float* __restrict__ wWo, const u16* __restrict__ WhT,
    u16* __restrict__ agg, u16* __restrict__ skub, float* __restrict__ skd)
{
  __shared__ __align__(16) float in_l[256];
  __shared__ __align__(16) float cps_l[512];
  __shared__ __align__(16) float gam_l[512];
  __shared__ __align__(16) float bet_l[512];
  __shared__ float aw_l[16];
  __shared__ __align__(16) u16 at_l[16*16*32];   // [h][b16][c32]
  __shared__ __align__(16) u16 ot_l[16*512];     // [b16][512]

  const int t = threadIdx.x;
  const int ln = t & 63;
  const long bb = (long)blockIdx.x * 16;

  in_l[t] = inputs[bb*16 + t];
  cps_l[t] = cps[t];       cps_l[t+256] = cps[t+256];
  gam_l[t] = ln_g[t];      gam_l[t+256] = ln_g[t+256];
  bet_l[t] = ln_b[t];      bet_l[t+256] = ln_b[t+256];
  if (t < 16) aw_l[t] = attnw[t];
  { // sku -> bf16 (16 rows x 64) + skd = sku . wWo per row
    const f32x4 sv = *(const f32x4*)&sku[bb*64 + t*4];
    unsigned lo = (unsigned)f2bf(sv.x) | ((unsigned)f2bf(sv.y) << 16);
    unsigned hi = (unsigned)f2bf(sv.z) | ((unsigned)f2bf(sv.w) << 16);
    unsigned long long v = (unsigned long long)lo | ((unsigned long long)hi << 32);
    *(unsigned long long*)&skub[bb*64 + t*4] = v;
    const f32x4 wv4 = *(const f32x4*)&wWo[(ln & 15)*4];
    float pd = sv.x*wv4.x + sv.y*wv4.y + sv.z*wv4.z + sv.w*wv4.w;
#pragma unroll
    for (int s = 1; s < 16; s <<= 1) pd += __shfl_xor(pd, s);
    if ((ln & 15) == 0) skd[bb + (t >> 4)] = pd;
  }
  __syncthreads();

  const int h = t >> 4, bi = t & 15;
  const float x = in_l[bi*16 + h];
  float nrm[NC], pw[NC];
  float s1 = 0.f;
#pragma unroll
  for (int c = 0; c < NC; c++){ float f = fmaxf(x - cps_l[h*NC + c], 0.f); nrm[c] = f; s1 += f; }
  const float mu = s1 * (1.f/NC);
  float s2 = 0.f;
#pragma unroll
  for (int c = 0; c < NC; c++){ float d = nrm[c] - mu; s2 += d*d; }
  const float rs = rsqrtf(s2 * (1.f/NC) + 1e-3f);
  const float aw = aw_l[h] * (1.0f/0.7f);
  float lmax = -1e30f;
#pragma unroll
  for (int c = 0; c < NC; c++){
    float nv = (nrm[c] - mu) * rs * gam_l[h*NC + c] + bet_l[h*NC + c];
    nrm[c] = nv;
    lmax = fmaxf(lmax, nv * aw);
  }
  float ps = 0.f;
#pragma unroll
  for (int c = 0; c < NC; c++){ float p = __expf(nrm[c]*aw - lmax); pw[c] = p; ps += p; }
  const float invs = 1.f / ps;
#pragma unroll
  for (int c = 0; c < NC; c += 2){
    unsigned pk = (unsigned)f2bf(nrm[c]*pw[c]*invs) | ((unsigned)f2bf(nrm[c+1]*pw[c+1]*invs) << 16);
    *(unsigned*)&at_l[h*512 + bi*32 + c] = pk;
  }
  __syncthreads();

  const int wv = t >> 6;
  const int lrow = ln & 15, lq = ln >> 4;
#pragma unroll
  for (int q = 0; q < 4; q++){
    const int hh = wv*4 + q;
    short8 af  = *(const short8*)&at_l[hh*512 + lrow*32 + lq*8];
    short8 bf0 = *(const short8*)&WhT[hh*1024 + lrow*32 + lq*8];
    short8 bf1 = *(const short8*)&WhT[hh*1024 + (16 + lrow)*32 + lq*8];
    f32x4 acc0 = {0.f,0.f,0.f,0.f}, acc1 = {0.f,0.f,0.f,0.f};
    acc0 = __builtin_amdgcn_mfma_f32_16x16x32_bf16(af, bf0, acc0, 0, 0, 0);
    acc1 = __builtin_amdgcn_mfma_f32_16x16x32_bf16(af, bf1, acc1, 0, 0, 0);
#pragma unroll
    for (int r = 0; r < 4; r++){
      const int br = lq*4 + r;
      ot_l[br*512 + hh*32 + lrow]      = f2bf(mishf(acc0[r]));
      ot_l[br*512 + hh*32 + 16 + lrow] = f2bf(mishf(acc1[r]));
    }
  }
  __syncthreads();
  {
    const int row = t >> 4, c16 = t & 15;
    const i32x4* src = (const i32x4*)&ot_l[row*512 + c16*32];
    i32x4* dst = (i32x4*)&agg[(bb + row)*512 + c16*32];
#pragma unroll
    for (int j = 0; j < 4; j++) dst[j] = src[j];
  }
}

// ---------------- gemm_bw: K=64 (128x128 skeleton): bw = f2h(sigmoid(skub@WbT) * Wo[n]) ----------------
__global__ __launch_bounds__(256, 3) void gemm_bw(
    const u16* __restrict__ A, const u16* __restrict__ Bt,
    const float* __restrict__ Wo, u16* __restrict__ bw)
{
  __shared__ __align__(16) u16 As[2][128*32];
  __shared__ __align__(16) u16 Bs[2][128*32];
  const int t = threadIdx.x, wv = t >> 6, ln = t & 63;
  const int g = blockIdx.x;
  const int m_idx = (g & 7) + ((g >> 5) << 3);
  const int n_idx = (g >> 3) & 3;
  const long m0 = (long)m_idx * 128;
  const int n0 = n_idx * 128;
  const int lrow = ln & 15, lq = ln >> 4;
  const int wm = wv >> 1, wn = wv & 1;

  auto stage = [&](int buf, int kt){
#pragma unroll
    for (int p = 0; p < 2; p++){
      const int chunk = p*256 + wv*64 + ln;
      const int mm = chunk >> 2, kc = chunk & 3;
      const int kcl = kc ^ ((mm >> 1) & 3);
      GLLDS(&A[(m0 + mm)*64 + kt + kcl*8],  &As[buf][(p*256 + wv*64)*8]);
      GLLDS(&Bt[(n0 + mm)*64 + kt + kcl*8], &Bs[buf][(p*256 + wv*64)*8]);
    }
  };

  f32x4 acc[4][4] = {};
  stage(0, 0);
  for (int ks = 0; ks < 2; ks++){
    const int cur = ks & 1;
    __syncthreads();
    if (ks + 1 < 2) stage(cur ^ 1, (ks + 1)*32);
    short8 a[4], b[4];
#pragma unroll
    for (int i = 0; i < 4; i++){
      const int ra = wm*64 + i*16 + lrow;
      const int rb = wn*64 + i*16 + lrow;
      const int lqa = lq ^ ((ra >> 1) & 3);
      const int lqb = lq ^ ((rb >> 1) & 3);
      a[i] = *(const short8*)&As[cur][ra*32 + lqa*8];
      b[i] = *(const short8*)&Bs[cur][rb*32 + lqb*8];
    }
#pragma unroll
    for (int i = 0; i < 4; i++)
#pragma unroll
      for (int j = 0; j < 4; j++)
        acc[i][j] = __builtin_amdgcn_mfma_f32_16x16x32_bf16(a[i], b[j], acc[i][j], 0, 0, 0);
  }
#pragma unroll
  for (int j = 0; j < 4; j++){
    const int n = n0 + wn*64 + j*16 + lrow;
    const float wo = Wo[n];
#pragma unroll
    for (int i = 0; i < 4; i++){
#pragma unroll
      for (int r = 0; r < 4; r++){
        const long m = m0 + wm*64 + i*16 + lq*4 + r;
        const float sig = 1.f / (1.f + __expf(-acc[i][j][r]));
        bw[m*512 + n] = f2h(sig * wo);
      }
    }
  }
}

// ---------------- gemm_mish: 128x512 tile, K=512. aggh = mish(agg@WahT); coalesced LDS-bounce stores ----------------
__global__ __launch_bounds__(512, 2) void gemm_mish(
    const u16* __restrict__ A, const u16* __restrict__ Bt, u16* __restrict__ aggh)
{
  __shared__ __align__(16) u16 lds[2*128*32 + 2*512*32];   // 80 KB union
  u16* As0 = lds;                  // [2][128*32]
  u16* Bs0 = lds + 2*128*32;       // [2][512*32]
  const int t = threadIdx.x, wv = t >> 6, ln = t & 63;
  const int lrow = ln & 15, lq = ln >> 4;
  const int rh = wv >> 2, cq = wv & 3;
  const long m0 = (long)blockIdx.x * 128;

  auto stageA = [&](int buf, int kt){
    const int mm = t >> 2, kc = t & 3;
    const int kcl = kc ^ ((mm >> 1) & 3);
    GLLDS(&A[(m0 + mm)*512 + kt + kcl*8], &As0[buf*4096 + t*8]);
  };
  auto stageB = [&](int buf, int kt){
#pragma unroll
    for (int p = 0; p < 4; p++){
      const int idx = p*512 + t;
      const int mm = idx >> 2, kc = idx & 3;
      const int kcl = kc ^ ((mm >> 1) & 3);
      GLLDS(&Bt[(long)mm*512 + kt + kcl*8], &Bs0[buf*16384 + idx*8]);
    }
  };

  f32x4 acc[4][8] = {};
  stageA(0, 0); stageB(0, 0);
  for (int ks = 0; ks < 16; ks++){
    const int cur = ks & 1;
    __syncthreads();
    if (ks + 1 < 16){ stageA(cur ^ 1, (ks + 1)*32); stageB(cur ^ 1, (ks + 1)*32); }
    short8 a[4], b[8];
#pragma unroll
    for (int i = 0; i < 4; i++){
      const int ra = rh*64 + i*16 + lrow;
      const int lqa = lq ^ ((ra >> 1) & 3);
      a[i] = *(const short8*)&As0[cur*4096 + ra*32 + lqa*8];
    }
#pragma unroll
    for (int j = 0; j < 8; j++){
      const int rb = cq*128 + j*16 + lrow;
      const int lqb = lq ^ ((rb >> 1) & 3);
      b[j] = *(const short8*)&Bs0[cur*16384 + rb*32 + lqb*8];
    }
#pragma unroll
    for (int i = 0; i < 4; i++)
#pragma unroll
      for (int j = 0; j < 8; j++)
        acc[i][j] = __builtin_amdgcn_mfma_f32_16x16x32_bf16(a[i], b[j], acc[i][j], 0, 0, 0);
  }

  // ---- coalesced epilogue: scatter 64-row half into padded LDS tile, stream out dwordx4 ----
  const int TP = 528;   // padded row (u16): 1056 B = 264 dwords; 264 % 32 = 8 -> lq rows land on distinct bank groups
  __syncthreads();
#pragma unroll 1
  for (int h = 0; h < 2; h++){
    if (rh == h){
#pragma unroll
      for (int i = 0; i < 4; i++)
#pragma unroll
        for (int j = 0; j < 8; j++)
#pragma unroll
          for (int r = 0; r < 4; r++)
            lds[(i*16 + lq*4 + r)*TP + cq*128 + j*16 + lrow] = f2bf(mishf(acc[i][j][r]));
    }
    __syncthreads();
#pragma unroll
    for (int it = 0; it < 8; it++){
      const int idx = it*512 + t;
      const int row = idx >> 6, off = idx & 63;
      const i32x4 v = *(const i32x4*)&lds[row*TP + off*8];
      *(i32x4*)&aggh[(m0 + h*64 + row)*512 + off*8] = v;
    }
    __syncthreads();
  }
}

// ---------------- mega2: 128x512 tile, K=512. logits = aggh@WaaT -> softmax(/0.7) -> out = sum(attn*aggh*bw)+skd ----------------
__global__ __launch_bounds__(512, 2) void mega2(
    const u16* __restrict__ A, const u16* __restrict__ Bt,
    const u16* __restrict__ bw, const float* __restrict__ skd,
    float* __restrict__ outp)
{
  __shared__ __align__(16) u16 As[2][128*32];
  __shared__ __align__(16) u16 Bs[2][512*32];
  const int t = threadIdx.x, wv = t >> 6, ln = t & 63;
  const int lrow = ln & 15, lq = ln >> 4;
  const int rh = wv >> 2, cq = wv & 3;
  const long m0 = (long)blockIdx.x * 128;

  auto stageA = [&](int buf, int kt){
    const int mm = t >> 2, kc = t & 3;
    const int kcl = kc ^ ((mm >> 1) & 3);
    GLLDS(&A[(m0 + mm)*512 + kt + kcl*8], &As[buf][t*8]);
  };
  auto stageB = [&](int buf, int kt){
#pragma unroll
    for (int p = 0; p < 4; p++){
      const int idx = p*512 + t;
      const int mm = idx >> 2, kc = idx & 3;
      const int kcl = kc ^ ((mm >> 1) & 3);
      GLLDS(&Bt[(long)mm*512 + kt + kcl*8], &Bs[buf][idx*8]);
    }
  };

  f32x4 acc[4][8] = {};
  stageA(0, 0); stageB(0, 0);
  for (int ks = 0; ks < 16; ks++){
    const int cur = ks & 1;
    __syncthreads();
    if (ks + 1 < 16){ stageA(cur ^ 1, (ks + 1)*32); stageB(cur ^ 1, (ks + 1)*32); }
    short8 a[4], b[8];
#pragma unroll
    for (int i = 0; i < 4; i++){
      const int ra = rh*64 + i*16 + lrow;
      const int lqa = lq ^ ((ra >> 1) & 3);
      a[i] = *(const short8*)&As[cur][ra*32 + lqa*8];
    }
#pragma unroll
    for (int j = 0; j < 8; j++){
      const int rb = cq*128 + j*16 + lrow;
      const int lqb = lq ^ ((rb >> 1) & 3);
      b[j] = *(const short8*)&Bs[cur][rb*32 + lqb*8];
    }
#pragma unroll
    for (int i = 0; i < 4; i++)
#pragma unroll
      for (int j = 0; j < 8; j++)
        acc[i][j] = __builtin_amdgcn_mfma_f32_16x16x32_bf16(a[i], b[j], acc[i][j], 0, 0, 0);
  }

  // ---- softmax + weighted-sum epilogue; stats overlay in dead Bs buffer ----
  __syncthreads();
  float* mxs = (float*)&Bs[0][0];   // [128][4]
  float* sss = mxs + 512;           // [128][4]
  float* tts = sss + 512;           // [128][4]
  const float inv_t = 1.0f / 0.7f;

#pragma unroll
  for (int i = 0; i < 4; i++){
#pragma unroll
    for (int r = 0; r < 4; r++){
      float tm = acc[i][0][r];
#pragma unroll
      for (int j = 1; j < 8; j++) tm = fmaxf(tm, acc[i][j][r]);
#pragma unroll
      for (int s = 1; s < 16; s <<= 1) tm = fmaxf(tm, __shfl_xor(tm, s));
      if (lrow == 0) mxs[(rh*64 + i*16 + lq*4 + r)*4 + cq] = tm;
    }
  }
  __syncthreads();
#pragma unroll
  for (int i = 0; i < 4; i++){
#pragma unroll
    for (int r = 0; r < 4; r++){
      const int row = rh*64 + i*16 + lq*4 + r;
      const float gm = fmaxf(fmaxf(mxs[row*4+0], mxs[row*4+1]),
                             fmaxf(mxs[row*4+2], mxs[row*4+3]));
      float sp = 0.f, tp = 0.f;
#pragma unroll
      for (int j = 0; j < 8; j++){
        const long gi = (m0 + row)*512 + cq*128 + j*16 + lrow;
        const float e = __expf((acc[i][j][r] - gm) * inv_t);
        sp += e;
        tp += e * bf2f(A[gi]) * h2f(bw[gi]);
      }
#pragma unroll
      for (int s = 1; s < 16; s <<= 1){ sp += __shfl_xor(sp, s); tp += __shfl_xor(tp, s); }
      if (lrow == 0){ sss[row*4 + cq] = sp; tts[row*4 + cq] = tp; }
    }
  }
  __syncthreads();
  if (t < 128){
    const float S = sss[t*4] + sss[t*4+1] + sss[t*4+2] + sss[t*4+3];
    const float T = tts[t*4] + tts[t*4+1] + tts[t*4+2] + tts[t*4+3];
    outp[m0 + t] = T / S + skd[m0 + t];
  }
}

__global__ void ws_too_small(float* o, float v){ o[(long)blockIdx.x*256 + threadIdx.x] = v; }

extern "C" void kernel_launch(void* const* d_in, const int* in_sizes, int n_in,
                              void* d_out, int out_size, void* d_ws, size_t ws_size,
                              hipStream_t stream)
{
  const float* inputs = (const float*)d_in[0];
  const float* sku    = (const float*)d_in[1];
  const float* deltas = (const float*)d_in[2];
  const float* ln_g   = (const float*)d_in[3];
  const float* ln_b   = (const float*)d_in[4];
  const float* attnw  = (const float*)d_in[5];
  const float* Wh     = (const float*)d_in[6];
  const float* Wah    = (const float*)d_in[7];
  const float* Waa    = (const float*)d_in[8];
  const float* Wb     = (const float*)d_in[9];
  const float* Wa     = (const float*)d_in[10];
  const float* Wo     = (const float*)d_in[11];
  float* outp = (float*)d_out;

  const size_t OFF_CPS  = 0;
  const size_t OFF_WWO  = 2048;
  const size_t OFF_WAHT = 4096;
  const size_t OFF_WAAT = OFF_WAHT + 524288;
  const size_t OFF_WBT  = OFF_WAAT + 524288;
  const size_t OFF_WHT  = OFF_WBT  + 65536;
  const size_t OFF_SKUB = OFF_WHT  + 32768;
  const size_t OFF_SKD  = OFF_SKUB + (size_t)CHUNK*64*2;
  const size_t OFF_AGG  = OFF_SKD  + (size_t)CHUNK*4;
  const size_t OFF_BW   = OFF_AGG  + (size_t)CHUNK*512*2;
  const size_t OFF_AGH  = OFF_BW   + (size_t)CHUNK*512*2;
  const size_t NEED     = OFF_AGH  + (size_t)CHUNK*512*2;  // ~211 MB

  if (ws_size < NEED){
    hipLaunchKernelGGL(ws_too_small, dim3(B_TOT/256), dim3(256), 0, stream,
                       outp, -(float)(ws_size >> 20));
    return;
  }

  char* ws = (char*)d_ws;
  float* cps  = (float*)(ws + OFF_CPS);
  float* wWo  = (float*)(ws + OFF_WWO);
  u16* WahT   = (u16*)(ws + OFF_WAHT);
  u16* WaaT   = (u16*)(ws + OFF_WAAT);
  u16* WbT    = (u16*)(ws + OFF_WBT);
  u16* WhT    = (u16*)(ws + OFF_WHT);
  u16* skub   = (u16*)(ws + OFF_SKUB);
  float* skd  = (float*)(ws + OFF_SKD);
  u16* agg    = (u16*)(ws + OFF_AGG);
  u16* bw     = (u16*)(ws + OFF_BW);
  u16* aggh   = (u16*)(ws + OFF_AGH);

  hipLaunchKernelGGL(prep_small, dim3(1), dim3(128), 0, stream, deltas, Wa, Wo, cps, wWo);
  hipLaunchKernelGGL(prep_convert, dim3(2240), dim3(256), 0, stream,
                     Wah, Waa, Wb, Wh, WahT, WaaT, WbT, WhT);

  for (int ch = 0; ch < B_TOT / CHUNK; ch++){
    const float* in_c  = inputs + (size_t)ch * CHUNK * 16;
    const float* sku_c = sku    + (size_t)ch * CHUNK * 64;
    float* out_c       = outp   + (size_t)ch * CHUNK;

    hipLaunchKernelGGL(stage1_kernel, dim3(CHUNK/16), dim3(256), 0, stream,
                       in_c, sku_c, ln_g, ln_b, attnw, cps, wWo, WhT, agg, skub, skd);
    hipLaunchKernelGGL(gemm_bw, dim3(CHUNK/128*4), dim3(256), 0, stream,
                       skub, WbT, Wo, bw);
    hipLaunchKernelGGL(gemm_mish, dim3(CHUNK/128), dim3(512), 0, stream,
                       agg, WahT, aggh);
    hipLaunchKernelGGL(mega2, dim3(CHUNK/128), dim3(512), 0, stream,
                       aggh, WaaT, bw, skd, out_c);
  }
}